// Round 5
// baseline (876.522 us; speedup 1.0000x reference)
//
#include <hip/hip_runtime.h>
#include <hip/hip_fp16.h>

// EquivSetGNN forward, MI355X.
// R5: break serial FMA accumulator chains in all readlane matmuls: 4 accumulators
// (k%4) x 2 rows per wave = 8 independent chains. The dependent-acc chain was
// limiting each wave to ~50% VALU issue and the 192-weight-VGPR kernels only fit
// 2 waves/SIMD, so TLP could not hide it. Compiler can't split float acc chains
// itself (no fast-math). CSR build / gathers unchanged from R4.

constexpr int NN = 100000;   // nodes
constexpr int NE = 50000;    // hyperedges
constexpr int NZ = 1280000;  // incidences
constexpr int NG = 256;      // graphs
constexpr int NB = (NE + 255) / 256;  // scan blocks

__device__ __forceinline__ float rl(float v, int k) {
  return __int_as_float(__builtin_amdgcn_readlane(__float_as_int(v), k));
}

__device__ __forceinline__ int lbound(const int* a, int n, int v) {
  int lo = 0, hi = n;
  while (lo < hi) { int m = (lo + hi) >> 1; if (a[m] < v) lo = m + 1; else hi = m; }
  return lo;
}

// 4-chain dot-product helper: acc = sum_k rl(a,k)*w[base+k], k in [0,64)
#define DOT64(a, w, base, out)                                   \
  {                                                              \
    float c0 = 0, c1 = 0, c2 = 0, c3 = 0;                        \
    _Pragma("unroll")                                            \
    for (int k = 0; k < 64; k += 4) {                            \
      c0 = fmaf(rl(a, k),     (w)[(base) + k],     c0);          \
      c1 = fmaf(rl(a, k + 1), (w)[(base) + k + 1], c1);          \
      c2 = fmaf(rl(a, k + 2), (w)[(base) + k + 2], c2);          \
      c3 = fmaf(rl(a, k + 3), (w)[(base) + k + 3], c3);          \
    }                                                            \
    out = (c0 + c1) + (c2 + c3);                                 \
  }

// ---- CSR-by-dst build ----
__global__ void count_k(const int* __restrict__ dst, int* __restrict__ cnt, int nnz) {
  int i = blockIdx.x * blockDim.x + threadIdx.x;
  if (i < nnz) atomicAdd(&cnt[dst[i]], 1);
}

__global__ void bsum_k(const int* __restrict__ cnt, int* __restrict__ bsum, int e) {
  __shared__ int red[256];
  int i = blockIdx.x * 256 + threadIdx.x;
  red[threadIdx.x] = (i < e) ? cnt[i] : 0;
  __syncthreads();
  for (int s = 128; s > 0; s >>= 1) {
    if (threadIdx.x < s) red[threadIdx.x] += red[threadIdx.x + s];
    __syncthreads();
  }
  if (threadIdx.x == 0) bsum[blockIdx.x] = red[0];
}

__global__ void bscan_k(int* __restrict__ bsum, int nb) {
  __shared__ int sh[256];
  int t = threadIdx.x;
  int my = (t < nb) ? bsum[t] : 0;
  sh[t] = my;
  __syncthreads();
  for (int ofs = 1; ofs < 256; ofs <<= 1) {
    int v = (t >= ofs) ? sh[t - ofs] : 0;
    __syncthreads();
    sh[t] += v;
    __syncthreads();
  }
  if (t < nb) bsum[t] = sh[t] - my;  // exclusive
}

__global__ void csroff_k(const int* __restrict__ cnt, const int* __restrict__ bsum,
                         int* __restrict__ off, int* __restrict__ cursor,
                         float* __restrict__ invE, int e) {
  __shared__ int sh[256];
  int t = threadIdx.x;
  int i = blockIdx.x * 256 + t;
  int c = (i < e) ? cnt[i] : 0;
  sh[t] = c;
  __syncthreads();
  for (int ofs = 1; ofs < 256; ofs <<= 1) {
    int v = (t >= ofs) ? sh[t - ofs] : 0;
    __syncthreads();
    sh[t] += v;
    __syncthreads();
  }
  int excl = sh[t] - c + bsum[blockIdx.x];
  if (i < e) {
    off[i] = excl;
    cursor[i] = excl;
    invE[i] = 1.0f / (float)max(c, 1);
  }
}

__global__ void fill_k(const int* __restrict__ src, const int* __restrict__ dst,
                       int* __restrict__ cursor, int* __restrict__ csr, int nnz) {
  int i = blockIdx.x * blockDim.x + threadIdx.x;
  if (i < nnz) { int p = atomicAdd(&cursor[dst[i]], 1); csr[p] = src[i]; }
}

__global__ void rowoff_diff_k(const int* __restrict__ src, int* __restrict__ roff,
                              int n, int nnz) {
  int i = blockIdx.x * blockDim.x + threadIdx.x;
  if (i >= nnz) return;
  int s = src[i];
  int prev = (i == 0) ? -1 : src[i - 1];
  for (int v = prev + 1; v <= s; ++v) roff[v] = i;
  if (i == nnz - 1) {
    for (int v = s + 1; v <= n; ++v) roff[v] = nnz;
  }
}

// ---- x = relu(X @ W_in + b_in); copy to x0. K=128, 2 rows/wave ----
__global__ void __launch_bounds__(256) mm_in_k(const float* __restrict__ A,
    const float* __restrict__ W, const float* __restrict__ b,
    float* __restrict__ C, float* __restrict__ C2, int n) {
  int lane = threadIdx.x & 63;
  int wid = (blockIdx.x * blockDim.x + threadIdx.x) >> 6;
  int nw = (gridDim.x * blockDim.x) >> 6;
  float w[128];
#pragma unroll
  for (int k = 0; k < 128; ++k) w[k] = W[k * 64 + lane];
  float bb = b[lane];
  for (int r0 = wid; r0 < n; r0 += 2 * nw) {
    int r1 = r0 + nw;
    bool has1 = r1 < n;
    float alo0 = A[(size_t)r0 * 128 + lane];
    float ahi0 = A[(size_t)r0 * 128 + 64 + lane];
    float alo1 = has1 ? A[(size_t)r1 * 128 + lane] : 0.0f;
    float ahi1 = has1 ? A[(size_t)r1 * 128 + 64 + lane] : 0.0f;
    float s0a, s0b, s1a, s1b;
    DOT64(alo0, w, 0, s0a); DOT64(ahi0, w, 64, s0b);
    DOT64(alo1, w, 0, s1a); DOT64(ahi1, w, 64, s1b);
    float v0 = fmaxf(bb + s0a + s0b, 0.0f);
    C[(size_t)r0 * 64 + lane] = v0;
    C2[(size_t)r0 * 64 + lane] = v0;
    if (has1) {
      float v1 = fmaxf(bb + s1a + s1b, 0.0f);
      C[(size_t)r1 * 64 + lane] = v1;
      C2[(size_t)r1 * 64 + lane] = v1;
    }
  }
}

// ---- h = relu(x@W1a+b1a)@W1b + b1b  (fp16 output), 2 rows/wave ----
__global__ void __launch_bounds__(256) mm_dual_k(const float* __restrict__ x,
    const float* __restrict__ W1a, const float* __restrict__ b1a,
    const float* __restrict__ W1b, const float* __restrict__ b1b,
    __half* __restrict__ h, int n) {
  int lane = threadIdx.x & 63;
  int wid = (blockIdx.x * blockDim.x + threadIdx.x) >> 6;
  int nw = (gridDim.x * blockDim.x) >> 6;
  float wa[64], wb[64];
#pragma unroll
  for (int k = 0; k < 64; ++k) wa[k] = W1a[k * 64 + lane];
#pragma unroll
  for (int k = 0; k < 64; ++k) wb[k] = W1b[k * 64 + lane];
  float ba = b1a[lane], bbv = b1b[lane];
  for (int r0 = wid; r0 < n; r0 += 2 * nw) {
    int r1 = r0 + nw;
    bool has1 = r1 < n;
    float a0 = x[(size_t)r0 * 64 + lane];
    float a1 = has1 ? x[(size_t)r1 * 64 + lane] : 0.0f;
    float t0, t1;
    DOT64(a0, wa, 0, t0); DOT64(a1, wa, 0, t1);
    t0 = fmaxf(ba + t0, 0.0f);
    t1 = fmaxf(ba + t1, 0.0f);
    float o0, o1;
    DOT64(t0, wb, 0, o0); DOT64(t1, wb, 0, o1);
    h[(size_t)r0 * 64 + lane] = __float2half(bbv + o0);
    if (has1) h[(size_t)r1 * 64 + lane] = __float2half(bbv + o1);
  }
}

// ---- V->E pull: Xe[e] = invE[e] * sum h[csr[...]]  (fp16 in/out) ----
__global__ void __launch_bounds__(256) ve_pull_k(const __half* __restrict__ h,
    const int* __restrict__ csr, const int* __restrict__ off, const int* __restrict__ cnt,
    const float* __restrict__ invE, __half* __restrict__ Xe, int e) {
  int lane = threadIdx.x & 63;
  int w = (blockIdx.x * blockDim.x + threadIdx.x) >> 6;
  if (w >= e) return;
  int lo = off[w], end = lo + cnt[w];
  float s0 = 0, s1 = 0, s2 = 0, s3 = 0, s4 = 0, s5 = 0, s6 = 0, s7 = 0;
  int i = lo;
  for (; i + 8 <= end; i += 8) {
    int e0 = csr[i], e1 = csr[i + 1], e2 = csr[i + 2], e3 = csr[i + 3];
    int e4 = csr[i + 4], e5 = csr[i + 5], e6 = csr[i + 6], e7 = csr[i + 7];
    s0 += __half2float(h[(size_t)e0 * 64 + lane]);
    s1 += __half2float(h[(size_t)e1 * 64 + lane]);
    s2 += __half2float(h[(size_t)e2 * 64 + lane]);
    s3 += __half2float(h[(size_t)e3 * 64 + lane]);
    s4 += __half2float(h[(size_t)e4 * 64 + lane]);
    s5 += __half2float(h[(size_t)e5 * 64 + lane]);
    s6 += __half2float(h[(size_t)e6 * 64 + lane]);
    s7 += __half2float(h[(size_t)e7 * 64 + lane]);
  }
  for (; i < end; ++i) s0 += __half2float(h[(size_t)csr[i] * 64 + lane]);
  float s = ((s0 + s1) + (s2 + s3)) + ((s4 + s5) + (s6 + s7));
  Xe[(size_t)w * 64 + lane] = __float2half(s * invE[w]);
}

// ---- E->V pull: z[v] = mean Xe[dst[...]]  (fp16 in/out) ----
__global__ void __launch_bounds__(256) zgather_k(const __half* __restrict__ Xe,
    const int* __restrict__ dstArr, const int* __restrict__ roff,
    __half* __restrict__ z, int n) {
  int lane = threadIdx.x & 63;
  int w = (blockIdx.x * blockDim.x + threadIdx.x) >> 6;
  if (w >= n) return;
  int lo = roff[w], hi = roff[w + 1];
  float s0 = 0, s1 = 0, s2 = 0, s3 = 0, s4 = 0, s5 = 0, s6 = 0, s7 = 0;
  int i = lo;
  for (; i + 8 <= hi; i += 8) {
    int e0 = dstArr[i], e1 = dstArr[i + 1], e2 = dstArr[i + 2], e3 = dstArr[i + 3];
    int e4 = dstArr[i + 4], e5 = dstArr[i + 5], e6 = dstArr[i + 6], e7 = dstArr[i + 7];
    s0 += __half2float(Xe[(size_t)e0 * 64 + lane]);
    s1 += __half2float(Xe[(size_t)e1 * 64 + lane]);
    s2 += __half2float(Xe[(size_t)e2 * 64 + lane]);
    s3 += __half2float(Xe[(size_t)e3 * 64 + lane]);
    s4 += __half2float(Xe[(size_t)e4 * 64 + lane]);
    s5 += __half2float(Xe[(size_t)e5 * 64 + lane]);
    s6 += __half2float(Xe[(size_t)e6 * 64 + lane]);
    s7 += __half2float(Xe[(size_t)e7 * 64 + lane]);
  }
  for (; i < hi; ++i) s0 += __half2float(Xe[(size_t)dstArr[i] * 64 + lane]);
  float s = ((s0 + s1) + (s2 + s3)) + ((s4 + s5) + (s6 + s7));
  z[(size_t)w * 64 + lane] = __float2half((hi > lo) ? s / (float)(hi - lo) : 0.0f);
}

// ---- fused: res = 0.5*x0 + 0.5*(cat(x,z)@W2+b2) [masked]; x = relu(res@W3+b3) ----
// 2 rows/wave, 4-chain dots.
__global__ void __launch_bounds__(256) catmm_w3_k(float* x, const __half* __restrict__ z,
    const float* __restrict__ x0, const int* __restrict__ roff,
    const float* __restrict__ W2, const float* __restrict__ b2,
    const float* __restrict__ W3, const float* __restrict__ b3, int n) {
  int lane = threadIdx.x & 63;
  int wid = (blockIdx.x * blockDim.x + threadIdx.x) >> 6;
  int nw = (gridDim.x * blockDim.x) >> 6;
  float w2r[128], w3r[64];
#pragma unroll
  for (int k = 0; k < 128; ++k) w2r[k] = W2[k * 64 + lane];
#pragma unroll
  for (int k = 0; k < 64; ++k) w3r[k] = W3[k * 64 + lane];
  float bb2 = b2[lane], bb3 = b3[lane];
  for (int r0 = wid; r0 < n; r0 += 2 * nw) {
    int r1 = r0 + nw;
    bool has1 = r1 < n;
    float a0  = x[(size_t)r0 * 64 + lane];
    float zz0 = __half2float(z[(size_t)r0 * 64 + lane]);
    float x00 = x0[(size_t)r0 * 64 + lane];
    int  deg0 = roff[r0 + 1] - roff[r0];
    float a1  = has1 ? x[(size_t)r1 * 64 + lane] : 0.0f;
    float zz1 = has1 ? __half2float(z[(size_t)r1 * 64 + lane]) : 0.0f;
    float x01 = has1 ? x0[(size_t)r1 * 64 + lane] : 0.0f;
    int  deg1 = has1 ? (roff[r1 + 1] - roff[r1]) : 0;
    float pa0, pz0, pa1, pz1;
    DOT64(a0,  w2r, 0,  pa0); DOT64(zz0, w2r, 64, pz0);
    DOT64(a1,  w2r, 0,  pa1); DOT64(zz1, w2r, 64, pz1);
    float res0 = 0.5f * x00;
    res0 = (deg0 > 0) ? fmaf(0.5f, bb2 + pa0 + pz0, res0) : res0;
    float res1 = 0.5f * x01;
    res1 = (deg1 > 0) ? fmaf(0.5f, bb2 + pa1 + pz1, res1) : res1;
    float o0, o1;
    DOT64(res0, w3r, 0, o0); DOT64(res1, w3r, 0, o1);
    x[(size_t)r0 * 64 + lane] = fmaxf(bb3 + o0, 0.0f);
    if (has1) x[(size_t)r1 * 64 + lane] = fmaxf(bb3 + o1, 0.0f);
  }
}

// ---- classifier: out = relu(x@Wc1+bc1)@Wc2+bc2, 2 rows/wave ----
__global__ void __launch_bounds__(256) classifier_k(const float* __restrict__ x,
    const float* __restrict__ Wc1, const float* __restrict__ bc1,
    const float* __restrict__ Wc2, const float* __restrict__ bc2,
    float* __restrict__ out, int n) {
  int lane = threadIdx.x & 63;
  int j2 = lane & 31;
  int wid = (blockIdx.x * blockDim.x + threadIdx.x) >> 6;
  int nw = (gridDim.x * blockDim.x) >> 6;
  float w1[64], w2[64];
#pragma unroll
  for (int k = 0; k < 64; ++k) w1[k] = Wc1[k * 64 + lane];
#pragma unroll
  for (int k = 0; k < 64; ++k) w2[k] = Wc2[k * 32 + j2];
  float b1v = bc1[lane], b2v = bc2[j2];
  for (int r0 = wid; r0 < n; r0 += 2 * nw) {
    int r1 = r0 + nw;
    bool has1 = r1 < n;
    float a0 = x[(size_t)r0 * 64 + lane];
    float a1 = has1 ? x[(size_t)r1 * 64 + lane] : 0.0f;
    float t0, t1;
    DOT64(a0, w1, 0, t0); DOT64(a1, w1, 0, t1);
    t0 = fmaxf(b1v + t0, 0.0f);
    t1 = fmaxf(b1v + t1, 0.0f);
    float o0, o1;
    DOT64(t0, w2, 0, o0); DOT64(t1, w2, 0, o1);
    if (lane < 32) {
      out[(size_t)r0 * 32 + lane] = b2v + o0;
      if (has1) out[(size_t)r1 * 32 + lane] = b2v + o1;
    }
  }
}

// ---- per-graph mean readout over sorted batch ids ----
__global__ void __launch_bounds__(256) readout_k(const float* __restrict__ xc,
    const int* __restrict__ batch, int n, float* __restrict__ out) {
  __shared__ float part[8][32];
  int g = blockIdx.x;
  int lo = lbound(batch, n, g);
  int hi = lbound(batch, n, g + 1);
  int j = threadIdx.x & 31, r = threadIdx.x >> 5;
  float acc = 0.0f;
  for (int i = lo + r; i < hi; i += 8) acc += xc[(size_t)i * 32 + j];
  part[r][j] = acc;
  __syncthreads();
  if (threadIdx.x < 32) {
    float s = 0.0f;
#pragma unroll
    for (int rr = 0; rr < 8; ++rr) s += part[rr][j];
    out[g * 32 + j] = (hi > lo) ? s / (float)(hi - lo) : 0.0f;
  }
}

extern "C" void kernel_launch(void* const* d_in, const int* in_sizes, int n_in,
                              void* d_out, int out_size, void* d_ws, size_t ws_size,
                              hipStream_t stream) {
  const float* X    = (const float*)d_in[0];
  const int*   src  = (const int*)d_in[1];
  const int*   dst  = (const int*)d_in[2];
  const int*   batch= (const int*)d_in[3];
  const float* W_in = (const float*)d_in[4];
  const float* b_in = (const float*)d_in[5];
  const float* W1a  = (const float*)d_in[6];
  const float* b1a  = (const float*)d_in[7];
  const float* W1b  = (const float*)d_in[8];
  const float* b1b  = (const float*)d_in[9];
  const float* W2   = (const float*)d_in[10];
  const float* b2   = (const float*)d_in[11];
  const float* W3   = (const float*)d_in[12];
  const float* b3   = (const float*)d_in[13];
  const float* Wc1  = (const float*)d_in[14];
  const float* bc1  = (const float*)d_in[15];
  const float* Wc2  = (const float*)d_in[16];
  const float* bc2  = (const float*)d_in[17];
  float* out = (float*)d_out;

  // workspace layout (~80 MB)
  float* p  = (float*)d_ws;
  float* x  = p; p += (size_t)NN * 64;   // 25.6 MB
  float* x0 = p; p += (size_t)NN * 64;   // 25.6 MB
  __half* hz = (__half*)p; p += (size_t)NN * 32;  // 12.8 MB: h, then z, then classifier out
  __half* Xe = (__half*)p; p += (size_t)NE * 32;  // 6.4 MB
  float* invE = p; p += NE;
  int* q     = (int*)p;
  int* cnt   = q; q += NE;
  int* off   = q; q += NE;
  int* cursor= q; q += NE;
  int* roff  = q; q += NN + 1;
  int* csr   = q; q += NZ;               // 5.12 MB
  int* bsum  = q; q += 256;
  __half* h = hz;
  __half* z = hz;              // alias: h fully consumed by ve_pull before zgather writes z
  float* outc = (float*)hz;    // alias: hz dead after last catmm_w3

  // CSR-by-dst + row offsets (once per call)
  hipMemsetAsync(cnt, 0, (size_t)NE * sizeof(int), stream);
  count_k<<<(NZ + 255) / 256, 256, 0, stream>>>(dst, cnt, NZ);
  bsum_k<<<NB, 256, 0, stream>>>(cnt, bsum, NE);
  bscan_k<<<1, 256, 0, stream>>>(bsum, NB);
  csroff_k<<<NB, 256, 0, stream>>>(cnt, bsum, off, cursor, invE, NE);
  fill_k<<<(NZ + 255) / 256, 256, 0, stream>>>(src, dst, cursor, csr, NZ);
  rowoff_diff_k<<<(NZ + 255) / 256, 256, 0, stream>>>(src, roff, NN, NZ);

  mm_in_k<<<1024, 256, 0, stream>>>(X, W_in, b_in, x, x0, NN);

  for (int l = 0; l < 2; ++l) {
    mm_dual_k<<<2048, 256, 0, stream>>>(x, W1a, b1a, W1b, b1b, h, NN);
    ve_pull_k<<<(NE + 3) / 4, 256, 0, stream>>>(h, csr, off, cnt, invE, Xe, NE);
    zgather_k<<<(NN + 3) / 4, 256, 0, stream>>>(Xe, dst, roff, z, NN);
    catmm_w3_k<<<2048, 256, 0, stream>>>(x, z, x0, roff, W2, b2, W3, b3, NN);
  }

  classifier_k<<<2048, 256, 0, stream>>>(x, Wc1, bc1, Wc2, bc2, outc, NN);
  readout_k<<<NG, 256, 0, stream>>>(outc, batch, NN, out);
}

// Round 6
// 587.609 us; speedup vs baseline: 1.4917x; 1.4917x over previous
//
#include <hip/hip_runtime.h>
#include <hip/hip_fp16.h>

// EquivSetGNN forward, MI355X.
// R6: matmul family moved to MFMA (v_mfma_f32_16x16x32_f16). Weights pre-swizzled
// to B-fragment layout once per call; A loaded f32->fp16; chained matmuls fused
// via per-wave LDS round-trip (C-layout -> A-layout, stride-68 pad). Readlane
// matmuls removed (they cost 2 VALU instr/MAC; MFMA does 4096 MACs/instr).
// Gathers + CSR build unchanged from R4/R5.

constexpr int NN = 100000;   // nodes
constexpr int NE = 50000;    // hyperedges
constexpr int NZ = 1280000;  // incidences
constexpr int NG = 256;      // graphs
constexpr int NB = (NE + 255) / 256;
constexpr int NTILE = NN / 16;  // 6250 row-tiles of 16

typedef _Float16 h8 __attribute__((ext_vector_type(8)));
typedef float f4 __attribute__((ext_vector_type(4)));

// weight-fragment buffer offsets (in halves); each region 16B-aligned
constexpr int OFF_IN  = 0;      // W_in  128x64 -> 16 frags
constexpr int OFF_1A  = 8192;   // W1a    64x64 -> 8
constexpr int OFF_1B  = 12288;  // W1b    64x64 -> 8
constexpr int OFF_W2  = 16384;  // W2    128x64 -> 16
constexpr int OFF_W3  = 24576;  // W3     64x64 -> 8
constexpr int OFF_C1  = 28672;  // Wc1    64x64 -> 8
constexpr int OFF_C2  = 32768;  // Wc2    64x32 -> 4
constexpr int WBUF_HALVES = 34816;

__device__ __forceinline__ int lbound(const int* a, int n, int v) {
  int lo = 0, hi = n;
  while (lo < hi) { int m = (lo + hi) >> 1; if (a[m] < v) lo = m + 1; else hi = m; }
  return lo;
}

__device__ __forceinline__ f4 zero4() { f4 z; z[0]=0.f; z[1]=0.f; z[2]=0.f; z[3]=0.f; return z; }

// load A-fragment from f32 row-major source: lane covers row m, cols k0..k0+7
__device__ __forceinline__ h8 ld_a32(const float* p) {
  const f4* v = (const f4*)p;
  f4 lo = v[0], hi = v[1];
  h8 r;
  r[0]=(_Float16)lo[0]; r[1]=(_Float16)lo[1]; r[2]=(_Float16)lo[2]; r[3]=(_Float16)lo[3];
  r[4]=(_Float16)hi[0]; r[5]=(_Float16)hi[1]; r[6]=(_Float16)hi[2]; r[7]=(_Float16)hi[3];
  return r;
}

#define MFMA(a, b, c) __builtin_amdgcn_mfma_f32_16x16x32_f16((a), (b), (c), 0, 0, 0)

// ---- CSR-by-dst build (unchanged) ----
__global__ void count_k(const int* __restrict__ dst, int* __restrict__ cnt, int nnz) {
  int i = blockIdx.x * blockDim.x + threadIdx.x;
  if (i < nnz) atomicAdd(&cnt[dst[i]], 1);
}

__global__ void bsum_k(const int* __restrict__ cnt, int* __restrict__ bsum, int e) {
  __shared__ int red[256];
  int i = blockIdx.x * 256 + threadIdx.x;
  red[threadIdx.x] = (i < e) ? cnt[i] : 0;
  __syncthreads();
  for (int s = 128; s > 0; s >>= 1) {
    if (threadIdx.x < s) red[threadIdx.x] += red[threadIdx.x + s];
    __syncthreads();
  }
  if (threadIdx.x == 0) bsum[blockIdx.x] = red[0];
}

__global__ void bscan_k(int* __restrict__ bsum, int nb) {
  __shared__ int sh[256];
  int t = threadIdx.x;
  int my = (t < nb) ? bsum[t] : 0;
  sh[t] = my;
  __syncthreads();
  for (int ofs = 1; ofs < 256; ofs <<= 1) {
    int v = (t >= ofs) ? sh[t - ofs] : 0;
    __syncthreads();
    sh[t] += v;
    __syncthreads();
  }
  if (t < nb) bsum[t] = sh[t] - my;
}

__global__ void csroff_k(const int* __restrict__ cnt, const int* __restrict__ bsum,
                         int* __restrict__ off, int* __restrict__ cursor,
                         float* __restrict__ invE, int e) {
  __shared__ int sh[256];
  int t = threadIdx.x;
  int i = blockIdx.x * 256 + t;
  int c = (i < e) ? cnt[i] : 0;
  sh[t] = c;
  __syncthreads();
  for (int ofs = 1; ofs < 256; ofs <<= 1) {
    int v = (t >= ofs) ? sh[t - ofs] : 0;
    __syncthreads();
    sh[t] += v;
    __syncthreads();
  }
  int excl = sh[t] - c + bsum[blockIdx.x];
  if (i < e) {
    off[i] = excl;
    cursor[i] = excl;
    invE[i] = 1.0f / (float)max(c, 1);
  }
}

__global__ void fill_k(const int* __restrict__ src, const int* __restrict__ dst,
                       int* __restrict__ cursor, int* __restrict__ csr, int nnz) {
  int i = blockIdx.x * blockDim.x + threadIdx.x;
  if (i < nnz) { int p = atomicAdd(&cursor[dst[i]], 1); csr[p] = src[i]; }
}

__global__ void rowoff_diff_k(const int* __restrict__ src, int* __restrict__ roff,
                              int n, int nnz) {
  int i = blockIdx.x * blockDim.x + threadIdx.x;
  if (i >= nnz) return;
  int s = src[i];
  int prev = (i == 0) ? -1 : src[i - 1];
  for (int v = prev + 1; v <= s; ++v) roff[v] = i;
  if (i == nnz - 1) {
    for (int v = s + 1; v <= n; ++v) roff[v] = nnz;
  }
}

// ---- weight prep: swizzle all weights into B-fragment fp16 layout ----
// frag layout: dst[((jt*KS + ks)*64 + lane)*8 + j] = W[(ks*32 + (lane>>4)*8 + j)*J + jt*16 + (lane&15)]
__global__ void prep_w_k(const float* __restrict__ W_in, const float* __restrict__ W1a,
                         const float* __restrict__ W1b, const float* __restrict__ W2,
                         const float* __restrict__ W3,  const float* __restrict__ Wc1,
                         const float* __restrict__ Wc2, _Float16* __restrict__ wbuf) {
  int b = blockIdx.x, l = threadIdx.x;
  const float* src; int K, J; _Float16* dst; int tile;
  if      (b < 16) { src = W_in; K = 128; J = 64; dst = wbuf + OFF_IN; tile = b; }
  else if (b < 24) { src = W1a;  K = 64;  J = 64; dst = wbuf + OFF_1A; tile = b - 16; }
  else if (b < 32) { src = W1b;  K = 64;  J = 64; dst = wbuf + OFF_1B; tile = b - 24; }
  else if (b < 48) { src = W2;   K = 128; J = 64; dst = wbuf + OFF_W2; tile = b - 32; }
  else if (b < 56) { src = W3;   K = 64;  J = 64; dst = wbuf + OFF_W3; tile = b - 48; }
  else if (b < 64) { src = Wc1;  K = 64;  J = 64; dst = wbuf + OFF_C1; tile = b - 56; }
  else             { src = Wc2;  K = 64;  J = 32; dst = wbuf + OFF_C2; tile = b - 64; }
  int KS = K / 32;
  int jt = tile / KS, ks = tile % KS;
  int q = l >> 4, m = l & 15;
#pragma unroll
  for (int j = 0; j < 8; ++j)
    dst[((size_t)tile * 64 + l) * 8 + j] =
        (_Float16)src[(size_t)(ks * 32 + q * 8 + j) * J + jt * 16 + m];
}

// ---- x = relu(X @ W_in + b); x0 = x. K=128, MFMA ----
__global__ void __launch_bounds__(256) mm_in_mfma(const float* __restrict__ A,
    const _Float16* __restrict__ wbuf, const float* __restrict__ b,
    float* __restrict__ C, float* __restrict__ C2, int ntiles) {
  int l = threadIdx.x & 63, q = l >> 4, m16 = l & 15;
  int wid = (blockIdx.x * blockDim.x + threadIdx.x) >> 6;
  int nw = (gridDim.x * blockDim.x) >> 6;
  const h8* wf = (const h8*)(wbuf + OFF_IN);
  h8 w[16];
#pragma unroll
  for (int f = 0; f < 16; ++f) w[f] = wf[f * 64 + l];
  float bv[4];
#pragma unroll
  for (int jt = 0; jt < 4; ++jt) bv[jt] = b[jt * 16 + m16];
  for (int t = wid; t < ntiles; t += nw) {
    int rbase = t * 16;
    const float* rp = A + (size_t)(rbase + m16) * 128 + q * 8;
    h8 a0 = ld_a32(rp), a1 = ld_a32(rp + 32), a2 = ld_a32(rp + 64), a3 = ld_a32(rp + 96);
    f4 acc[4];
#pragma unroll
    for (int jt = 0; jt < 4; ++jt) {
      acc[jt] = zero4();
      acc[jt] = MFMA(a0, w[jt * 4 + 0], acc[jt]);
      acc[jt] = MFMA(a1, w[jt * 4 + 1], acc[jt]);
      acc[jt] = MFMA(a2, w[jt * 4 + 2], acc[jt]);
      acc[jt] = MFMA(a3, w[jt * 4 + 3], acc[jt]);
    }
#pragma unroll
    for (int jt = 0; jt < 4; ++jt)
#pragma unroll
      for (int r = 0; r < 4; ++r) {
        float v = fmaxf(acc[jt][r] + bv[jt], 0.0f);
        size_t idx = (size_t)(rbase + q * 4 + r) * 64 + jt * 16 + m16;
        C[idx] = v; C2[idx] = v;
      }
  }
}

// ---- h = relu(x@W1a+b1a)@W1b + b1b  (fp16 out), MFMA + LDS transpose ----
__global__ void __launch_bounds__(256) mm_dual_mfma(const float* __restrict__ x,
    const _Float16* __restrict__ wbuf, const float* __restrict__ b1a,
    const float* __restrict__ b1b, __half* __restrict__ h, int ntiles) {
  __shared__ float lds[4][16 * 68];
  int l = threadIdx.x & 63, q = l >> 4, m16 = l & 15, wv = threadIdx.x >> 6;
  int wid = (blockIdx.x * blockDim.x + threadIdx.x) >> 6;
  int nw = (gridDim.x * blockDim.x) >> 6;
  const h8* wap = (const h8*)(wbuf + OFF_1A);
  const h8* wbp = (const h8*)(wbuf + OFF_1B);
  h8 wa[8], wb[8];
#pragma unroll
  for (int f = 0; f < 8; ++f) { wa[f] = wap[f * 64 + l]; wb[f] = wbp[f * 64 + l]; }
  float bav[4], bbv[4];
#pragma unroll
  for (int jt = 0; jt < 4; ++jt) { bav[jt] = b1a[jt * 16 + m16]; bbv[jt] = b1b[jt * 16 + m16]; }
  float* myl = lds[wv];
  for (int t = wid; t < ntiles; t += nw) {
    int rbase = t * 16;
    const float* rp = x + (size_t)(rbase + m16) * 64 + q * 8;
    h8 a0 = ld_a32(rp), a1 = ld_a32(rp + 32);
    f4 acc[4];
#pragma unroll
    for (int jt = 0; jt < 4; ++jt) {
      acc[jt] = zero4();
      acc[jt] = MFMA(a0, wa[jt * 2 + 0], acc[jt]);
      acc[jt] = MFMA(a1, wa[jt * 2 + 1], acc[jt]);
    }
#pragma unroll
    for (int jt = 0; jt < 4; ++jt)
#pragma unroll
      for (int r = 0; r < 4; ++r)
        myl[(q * 4 + r) * 68 + jt * 16 + m16] = fmaxf(acc[jt][r] + bav[jt], 0.0f);
    h8 t0, t1;
#pragma unroll
    for (int j = 0; j < 8; ++j) t0[j] = (_Float16)myl[m16 * 68 + q * 8 + j];
#pragma unroll
    for (int j = 0; j < 8; ++j) t1[j] = (_Float16)myl[m16 * 68 + 32 + q * 8 + j];
#pragma unroll
    for (int jt = 0; jt < 4; ++jt) {
      acc[jt] = zero4();
      acc[jt] = MFMA(t0, wb[jt * 2 + 0], acc[jt]);
      acc[jt] = MFMA(t1, wb[jt * 2 + 1], acc[jt]);
    }
#pragma unroll
    for (int jt = 0; jt < 4; ++jt)
#pragma unroll
      for (int r = 0; r < 4; ++r)
        h[(size_t)(rbase + q * 4 + r) * 64 + jt * 16 + m16] = __float2half(acc[jt][r] + bbv[jt]);
  }
}

// ---- V->E pull (unchanged) ----
__global__ void __launch_bounds__(256) ve_pull_k(const __half* __restrict__ h,
    const int* __restrict__ csr, const int* __restrict__ off, const int* __restrict__ cnt,
    const float* __restrict__ invE, __half* __restrict__ Xe, int e) {
  int lane = threadIdx.x & 63;
  int w = (blockIdx.x * blockDim.x + threadIdx.x) >> 6;
  if (w >= e) return;
  int lo = off[w], end = lo + cnt[w];
  float s0 = 0, s1 = 0, s2 = 0, s3 = 0, s4 = 0, s5 = 0, s6 = 0, s7 = 0;
  int i = lo;
  for (; i + 8 <= end; i += 8) {
    int e0 = csr[i], e1 = csr[i + 1], e2 = csr[i + 2], e3 = csr[i + 3];
    int e4 = csr[i + 4], e5 = csr[i + 5], e6 = csr[i + 6], e7 = csr[i + 7];
    s0 += __half2float(h[(size_t)e0 * 64 + lane]);
    s1 += __half2float(h[(size_t)e1 * 64 + lane]);
    s2 += __half2float(h[(size_t)e2 * 64 + lane]);
    s3 += __half2float(h[(size_t)e3 * 64 + lane]);
    s4 += __half2float(h[(size_t)e4 * 64 + lane]);
    s5 += __half2float(h[(size_t)e5 * 64 + lane]);
    s6 += __half2float(h[(size_t)e6 * 64 + lane]);
    s7 += __half2float(h[(size_t)e7 * 64 + lane]);
  }
  for (; i < end; ++i) s0 += __half2float(h[(size_t)csr[i] * 64 + lane]);
  float s = ((s0 + s1) + (s2 + s3)) + ((s4 + s5) + (s6 + s7));
  Xe[(size_t)w * 64 + lane] = __float2half(s * invE[w]);
}

// ---- E->V pull (unchanged) ----
__global__ void __launch_bounds__(256) zgather_k(const __half* __restrict__ Xe,
    const int* __restrict__ dstArr, const int* __restrict__ roff,
    __half* __restrict__ z, int n) {
  int lane = threadIdx.x & 63;
  int w = (blockIdx.x * blockDim.x + threadIdx.x) >> 6;
  if (w >= n) return;
  int lo = roff[w], hi = roff[w + 1];
  float s0 = 0, s1 = 0, s2 = 0, s3 = 0, s4 = 0, s5 = 0, s6 = 0, s7 = 0;
  int i = lo;
  for (; i + 8 <= hi; i += 8) {
    int e0 = dstArr[i], e1 = dstArr[i + 1], e2 = dstArr[i + 2], e3 = dstArr[i + 3];
    int e4 = dstArr[i + 4], e5 = dstArr[i + 5], e6 = dstArr[i + 6], e7 = dstArr[i + 7];
    s0 += __half2float(Xe[(size_t)e0 * 64 + lane]);
    s1 += __half2float(Xe[(size_t)e1 * 64 + lane]);
    s2 += __half2float(Xe[(size_t)e2 * 64 + lane]);
    s3 += __half2float(Xe[(size_t)e3 * 64 + lane]);
    s4 += __half2float(Xe[(size_t)e4 * 64 + lane]);
    s5 += __half2float(Xe[(size_t)e5 * 64 + lane]);
    s6 += __half2float(Xe[(size_t)e6 * 64 + lane]);
    s7 += __half2float(Xe[(size_t)e7 * 64 + lane]);
  }
  for (; i < hi; ++i) s0 += __half2float(Xe[(size_t)dstArr[i] * 64 + lane]);
  float s = ((s0 + s1) + (s2 + s3)) + ((s4 + s5) + (s6 + s7));
  z[(size_t)w * 64 + lane] = __float2half((hi > lo) ? s / (float)(hi - lo) : 0.0f);
}

// ---- fused: res = 0.5*x0 + mask*0.5*(cat(x,z)@W2+b2); x = relu(res@W3+b3). MFMA ----
__global__ void __launch_bounds__(256) catmm_w3_mfma(float* __restrict__ x,
    const __half* __restrict__ z, const float* __restrict__ x0,
    const int* __restrict__ roff, const _Float16* __restrict__ wbuf,
    const float* __restrict__ b2, const float* __restrict__ b3, int ntiles) {
  __shared__ float lds[4][16 * 68];
  int l = threadIdx.x & 63, q = l >> 4, m16 = l & 15, wv = threadIdx.x >> 6;
  int wid = (blockIdx.x * blockDim.x + threadIdx.x) >> 6;
  int nw = (gridDim.x * blockDim.x) >> 6;
  const h8* w2p = (const h8*)(wbuf + OFF_W2);
  const h8* w3p = (const h8*)(wbuf + OFF_W3);
  h8 w2[16], w3[8];
#pragma unroll
  for (int f = 0; f < 16; ++f) w2[f] = w2p[f * 64 + l];
#pragma unroll
  for (int f = 0; f < 8; ++f) w3[f] = w3p[f * 64 + l];
  float bv2[4], bv3[4];
#pragma unroll
  for (int jt = 0; jt < 4; ++jt) { bv2[jt] = b2[jt * 16 + m16]; bv3[jt] = b3[jt * 16 + m16]; }
  float* myl = lds[wv];
  for (int t = wid; t < ntiles; t += nw) {
    int rbase = t * 16;
    const float* rp = x + (size_t)(rbase + m16) * 64 + q * 8;
    h8 a0 = ld_a32(rp), a1 = ld_a32(rp + 32);
    const h8* zp = (const h8*)(z + (size_t)(rbase + m16) * 64 + q * 8);
    h8 az0 = zp[0], az1 = zp[2];  // +0 and +32 halves (h8 = 8 halves)
    f4 acc[4];
#pragma unroll
    for (int jt = 0; jt < 4; ++jt) {
      acc[jt] = zero4();
      acc[jt] = MFMA(a0,  w2[jt * 4 + 0], acc[jt]);
      acc[jt] = MFMA(a1,  w2[jt * 4 + 1], acc[jt]);
      acc[jt] = MFMA(az0, w2[jt * 4 + 2], acc[jt]);
      acc[jt] = MFMA(az1, w2[jt * 4 + 3], acc[jt]);
    }
#pragma unroll
    for (int r = 0; r < 4; ++r) {
      int row = rbase + q * 4 + r;
      float msk = (roff[row + 1] > roff[row]) ? 0.5f : 0.0f;
#pragma unroll
      for (int jt = 0; jt < 4; ++jt) {
        float val = acc[jt][r] + bv2[jt];
        float res = fmaf(msk, val, 0.5f * x0[(size_t)row * 64 + jt * 16 + m16]);
        myl[(q * 4 + r) * 68 + jt * 16 + m16] = res;
      }
    }
    h8 t0, t1;
#pragma unroll
    for (int j = 0; j < 8; ++j) t0[j] = (_Float16)myl[m16 * 68 + q * 8 + j];
#pragma unroll
    for (int j = 0; j < 8; ++j) t1[j] = (_Float16)myl[m16 * 68 + 32 + q * 8 + j];
#pragma unroll
    for (int jt = 0; jt < 4; ++jt) {
      acc[jt] = zero4();
      acc[jt] = MFMA(t0, w3[jt * 2 + 0], acc[jt]);
      acc[jt] = MFMA(t1, w3[jt * 2 + 1], acc[jt]);
    }
#pragma unroll
    for (int jt = 0; jt < 4; ++jt)
#pragma unroll
      for (int r = 0; r < 4; ++r)
        x[(size_t)(rbase + q * 4 + r) * 64 + jt * 16 + m16] = fmaxf(acc[jt][r] + bv3[jt], 0.0f);
  }
}

// ---- classifier: out = relu(x@Wc1+bc1)@Wc2+bc2 (J=32). MFMA ----
__global__ void __launch_bounds__(256) classifier_mfma(const float* __restrict__ x,
    const _Float16* __restrict__ wbuf, const float* __restrict__ bc1,
    const float* __restrict__ bc2, float* __restrict__ out, int ntiles) {
  __shared__ float lds[4][16 * 68];
  int l = threadIdx.x & 63, q = l >> 4, m16 = l & 15, wv = threadIdx.x >> 6;
  int wid = (blockIdx.x * blockDim.x + threadIdx.x) >> 6;
  int nw = (gridDim.x * blockDim.x) >> 6;
  const h8* w1p = (const h8*)(wbuf + OFF_C1);
  const h8* w2p = (const h8*)(wbuf + OFF_C2);
  h8 w1[8], w2[4];
#pragma unroll
  for (int f = 0; f < 8; ++f) w1[f] = w1p[f * 64 + l];
#pragma unroll
  for (int f = 0; f < 4; ++f) w2[f] = w2p[f * 64 + l];
  float bv1[4], bv2[2];
#pragma unroll
  for (int jt = 0; jt < 4; ++jt) bv1[jt] = bc1[jt * 16 + m16];
#pragma unroll
  for (int jt = 0; jt < 2; ++jt) bv2[jt] = bc2[jt * 16 + m16];
  float* myl = lds[wv];
  for (int t = wid; t < ntiles; t += nw) {
    int rbase = t * 16;
    const float* rp = x + (size_t)(rbase + m16) * 64 + q * 8;
    h8 a0 = ld_a32(rp), a1 = ld_a32(rp + 32);
    f4 acc[4];
#pragma unroll
    for (int jt = 0; jt < 4; ++jt) {
      acc[jt] = zero4();
      acc[jt] = MFMA(a0, w1[jt * 2 + 0], acc[jt]);
      acc[jt] = MFMA(a1, w1[jt * 2 + 1], acc[jt]);
    }
#pragma unroll
    for (int jt = 0; jt < 4; ++jt)
#pragma unroll
      for (int r = 0; r < 4; ++r)
        myl[(q * 4 + r) * 68 + jt * 16 + m16] = fmaxf(acc[jt][r] + bv1[jt], 0.0f);
    h8 t0, t1;
#pragma unroll
    for (int j = 0; j < 8; ++j) t0[j] = (_Float16)myl[m16 * 68 + q * 8 + j];
#pragma unroll
    for (int j = 0; j < 8; ++j) t1[j] = (_Float16)myl[m16 * 68 + 32 + q * 8 + j];
    f4 o[2];
#pragma unroll
    for (int jt = 0; jt < 2; ++jt) {
      o[jt] = zero4();
      o[jt] = MFMA(t0, w2[jt * 2 + 0], o[jt]);
      o[jt] = MFMA(t1, w2[jt * 2 + 1], o[jt]);
    }
#pragma unroll
    for (int jt = 0; jt < 2; ++jt)
#pragma unroll
      for (int r = 0; r < 4; ++r)
        out[(size_t)(rbase + q * 4 + r) * 32 + jt * 16 + m16] = o[jt][r] + bv2[jt];
  }
}

// ---- per-graph mean readout (unchanged) ----
__global__ void __launch_bounds__(256) readout_k(const float* __restrict__ xc,
    const int* __restrict__ batch, int n, float* __restrict__ out) {
  __shared__ float part[8][32];
  int g = blockIdx.x;
  int lo = lbound(batch, n, g);
  int hi = lbound(batch, n, g + 1);
  int j = threadIdx.x & 31, r = threadIdx.x >> 5;
  float acc = 0.0f;
  for (int i = lo + r; i < hi; i += 8) acc += xc[(size_t)i * 32 + j];
  part[r][j] = acc;
  __syncthreads();
  if (threadIdx.x < 32) {
    float s = 0.0f;
#pragma unroll
    for (int rr = 0; rr < 8; ++rr) s += part[rr][j];
    out[g * 32 + j] = (hi > lo) ? s / (float)(hi - lo) : 0.0f;
  }
}

extern "C" void kernel_launch(void* const* d_in, const int* in_sizes, int n_in,
                              void* d_out, int out_size, void* d_ws, size_t ws_size,
                              hipStream_t stream) {
  const float* X    = (const float*)d_in[0];
  const int*   src  = (const int*)d_in[1];
  const int*   dst  = (const int*)d_in[2];
  const int*   batch= (const int*)d_in[3];
  const float* W_in = (const float*)d_in[4];
  const float* b_in = (const float*)d_in[5];
  const float* W1a  = (const float*)d_in[6];
  const float* b1a  = (const float*)d_in[7];
  const float* W1b  = (const float*)d_in[8];
  const float* b1b  = (const float*)d_in[9];
  const float* W2   = (const float*)d_in[10];
  const float* b2   = (const float*)d_in[11];
  const float* W3   = (const float*)d_in[12];
  const float* b3   = (const float*)d_in[13];
  const float* Wc1  = (const float*)d_in[14];
  const float* bc1  = (const float*)d_in[15];
  const float* Wc2  = (const float*)d_in[16];
  const float* bc2  = (const float*)d_in[17];
  float* out = (float*)d_out;

  // workspace layout (~77 MB)
  float* p  = (float*)d_ws;
  float* x  = p; p += (size_t)NN * 64;            // 25.6 MB
  float* x0 = p; p += (size_t)NN * 64;            // 25.6 MB (aliased as classifier out later)
  __half* hz = (__half*)p; p += (size_t)NN * 32;  // 12.8 MB: h then z
  __half* Xe = (__half*)p; p += (size_t)NE * 32;  // 6.4 MB
  float* invE = p; p += NE;
  _Float16* wbuf = (_Float16*)p; p += WBUF_HALVES / 2 + 16;
  int* q     = (int*)p;
  int* cnt   = q; q += NE;
  int* off   = q; q += NE;
  int* cursor= q; q += NE;
  int* roff  = q; q += NN + 1;
  int* csr   = q; q += NZ;                        // 5.12 MB
  int* bsum  = q; q += 256;
  __half* h = hz;
  __half* z = hz;           // alias: h fully consumed by ve_pull before zgather writes z
  float* outc = x0;         // alias: x0 dead after last catmm_w3

  // CSR-by-dst + row offsets + weight prep (once per call)
  hipMemsetAsync(cnt, 0, (size_t)NE * sizeof(int), stream);
  count_k<<<(NZ + 255) / 256, 256, 0, stream>>>(dst, cnt, NZ);
  bsum_k<<<NB, 256, 0, stream>>>(cnt, bsum, NE);
  bscan_k<<<1, 256, 0, stream>>>(bsum, NB);
  csroff_k<<<NB, 256, 0, stream>>>(cnt, bsum, off, cursor, invE, NE);
  fill_k<<<(NZ + 255) / 256, 256, 0, stream>>>(src, dst, cursor, csr, NZ);
  rowoff_diff_k<<<(NZ + 255) / 256, 256, 0, stream>>>(src, roff, NN, NZ);
  prep_w_k<<<68, 64, 0, stream>>>(W_in, W1a, W1b, W2, W3, Wc1, Wc2, wbuf);

  mm_in_mfma<<<1563, 256, 0, stream>>>(X, wbuf, b_in, x, x0, NTILE);

  for (int l = 0; l < 2; ++l) {
    mm_dual_mfma<<<1563, 256, 0, stream>>>(x, wbuf, b1a, b1b, h, NTILE);
    ve_pull_k<<<(NE + 3) / 4, 256, 0, stream>>>(h, csr, off, cnt, invE, Xe, NE);
    zgather_k<<<(NN + 3) / 4, 256, 0, stream>>>(Xe, dst, roff, z, NN);
    catmm_w3_mfma<<<1563, 256, 0, stream>>>(x, z, x0, roff, wbuf, b2, b3, NTILE);
  }

  classifier_mfma<<<1563, 256, 0, stream>>>(x, wbuf, bc1, bc2, outc, NTILE);
  readout_k<<<NG, 256, 0, stream>>>(outc, batch, NN, out);
}

// Round 7
// 528.559 us; speedup vs baseline: 1.6583x; 1.1117x over previous
//
#include <hip/hip_runtime.h>
#include <hip/hip_fp16.h>

// EquivSetGNN forward, MI355X.
// R7: gather kernels restructured — lane (g=lane>>3,c=lane&7) loads 16B of row
// csr[i+g]: one VMEM instruction = 8 rows = 1KB (was 1 row / 128B). shfl_xor
// (8,16,32) tree-reduce across row-groups, lanes g==0 store the row. Same bytes,
// 8x fewer memory instructions. MFMA matmuls + CSR build unchanged from R6.

constexpr int NN = 100000;   // nodes
constexpr int NE = 50000;    // hyperedges
constexpr int NZ = 1280000;  // incidences
constexpr int NG = 256;      // graphs
constexpr int NB = (NE + 255) / 256;
constexpr int NTILE = NN / 16;  // 6250 row-tiles of 16

typedef _Float16 h8 __attribute__((ext_vector_type(8)));
typedef float f4 __attribute__((ext_vector_type(4)));

// weight-fragment buffer offsets (in halves); each region 16B-aligned
constexpr int OFF_IN  = 0;      // W_in  128x64 -> 16 frags
constexpr int OFF_1A  = 8192;   // W1a    64x64 -> 8
constexpr int OFF_1B  = 12288;  // W1b    64x64 -> 8
constexpr int OFF_W2  = 16384;  // W2    128x64 -> 16
constexpr int OFF_W3  = 24576;  // W3     64x64 -> 8
constexpr int OFF_C1  = 28672;  // Wc1    64x64 -> 8
constexpr int OFF_C2  = 32768;  // Wc2    64x32 -> 4
constexpr int WBUF_HALVES = 34816;

__device__ __forceinline__ int lbound(const int* a, int n, int v) {
  int lo = 0, hi = n;
  while (lo < hi) { int m = (lo + hi) >> 1; if (a[m] < v) lo = m + 1; else hi = m; }
  return lo;
}

__device__ __forceinline__ f4 zero4() { f4 z; z[0]=0.f; z[1]=0.f; z[2]=0.f; z[3]=0.f; return z; }

__device__ __forceinline__ h8 ld_a32(const float* p) {
  const f4* v = (const f4*)p;
  f4 lo = v[0], hi = v[1];
  h8 r;
  r[0]=(_Float16)lo[0]; r[1]=(_Float16)lo[1]; r[2]=(_Float16)lo[2]; r[3]=(_Float16)lo[3];
  r[4]=(_Float16)hi[0]; r[5]=(_Float16)hi[1]; r[6]=(_Float16)hi[2]; r[7]=(_Float16)hi[3];
  return r;
}

#define MFMA(a, b, c) __builtin_amdgcn_mfma_f32_16x16x32_f16((a), (b), (c), 0, 0, 0)

// ---- CSR-by-dst build (unchanged) ----
__global__ void count_k(const int* __restrict__ dst, int* __restrict__ cnt, int nnz) {
  int i = blockIdx.x * blockDim.x + threadIdx.x;
  if (i < nnz) atomicAdd(&cnt[dst[i]], 1);
}

__global__ void bsum_k(const int* __restrict__ cnt, int* __restrict__ bsum, int e) {
  __shared__ int red[256];
  int i = blockIdx.x * 256 + threadIdx.x;
  red[threadIdx.x] = (i < e) ? cnt[i] : 0;
  __syncthreads();
  for (int s = 128; s > 0; s >>= 1) {
    if (threadIdx.x < s) red[threadIdx.x] += red[threadIdx.x + s];
    __syncthreads();
  }
  if (threadIdx.x == 0) bsum[blockIdx.x] = red[0];
}

__global__ void bscan_k(int* __restrict__ bsum, int nb) {
  __shared__ int sh[256];
  int t = threadIdx.x;
  int my = (t < nb) ? bsum[t] : 0;
  sh[t] = my;
  __syncthreads();
  for (int ofs = 1; ofs < 256; ofs <<= 1) {
    int v = (t >= ofs) ? sh[t - ofs] : 0;
    __syncthreads();
    sh[t] += v;
    __syncthreads();
  }
  if (t < nb) bsum[t] = sh[t] - my;
}

__global__ void csroff_k(const int* __restrict__ cnt, const int* __restrict__ bsum,
                         int* __restrict__ off, int* __restrict__ cursor,
                         float* __restrict__ invE, int e) {
  __shared__ int sh[256];
  int t = threadIdx.x;
  int i = blockIdx.x * 256 + t;
  int c = (i < e) ? cnt[i] : 0;
  sh[t] = c;
  __syncthreads();
  for (int ofs = 1; ofs < 256; ofs <<= 1) {
    int v = (t >= ofs) ? sh[t - ofs] : 0;
    __syncthreads();
    sh[t] += v;
    __syncthreads();
  }
  int excl = sh[t] - c + bsum[blockIdx.x];
  if (i < e) {
    off[i] = excl;
    cursor[i] = excl;
    invE[i] = 1.0f / (float)max(c, 1);
  }
}

__global__ void fill_k(const int* __restrict__ src, const int* __restrict__ dst,
                       int* __restrict__ cursor, int* __restrict__ csr, int nnz) {
  int i = blockIdx.x * blockDim.x + threadIdx.x;
  if (i < nnz) { int p = atomicAdd(&cursor[dst[i]], 1); csr[p] = src[i]; }
}

__global__ void rowoff_diff_k(const int* __restrict__ src, int* __restrict__ roff,
                              int n, int nnz) {
  int i = blockIdx.x * blockDim.x + threadIdx.x;
  if (i >= nnz) return;
  int s = src[i];
  int prev = (i == 0) ? -1 : src[i - 1];
  for (int v = prev + 1; v <= s; ++v) roff[v] = i;
  if (i == nnz - 1) {
    for (int v = s + 1; v <= n; ++v) roff[v] = nnz;
  }
}

// ---- weight prep (unchanged) ----
__global__ void prep_w_k(const float* __restrict__ W_in, const float* __restrict__ W1a,
                         const float* __restrict__ W1b, const float* __restrict__ W2,
                         const float* __restrict__ W3,  const float* __restrict__ Wc1,
                         const float* __restrict__ Wc2, _Float16* __restrict__ wbuf) {
  int b = blockIdx.x, l = threadIdx.x;
  const float* src; int K, J; _Float16* dst; int tile;
  if      (b < 16) { src = W_in; K = 128; J = 64; dst = wbuf + OFF_IN; tile = b; }
  else if (b < 24) { src = W1a;  K = 64;  J = 64; dst = wbuf + OFF_1A; tile = b - 16; }
  else if (b < 32) { src = W1b;  K = 64;  J = 64; dst = wbuf + OFF_1B; tile = b - 24; }
  else if (b < 48) { src = W2;   K = 128; J = 64; dst = wbuf + OFF_W2; tile = b - 32; }
  else if (b < 56) { src = W3;   K = 64;  J = 64; dst = wbuf + OFF_W3; tile = b - 48; }
  else if (b < 64) { src = Wc1;  K = 64;  J = 64; dst = wbuf + OFF_C1; tile = b - 56; }
  else             { src = Wc2;  K = 64;  J = 32; dst = wbuf + OFF_C2; tile = b - 64; }
  int KS = K / 32;
  int jt = tile / KS, ks = tile % KS;
  int q = l >> 4, m = l & 15;
#pragma unroll
  for (int j = 0; j < 8; ++j)
    dst[((size_t)tile * 64 + l) * 8 + j] =
        (_Float16)src[(size_t)(ks * 32 + q * 8 + j) * J + jt * 16 + m];
}

// ---- x = relu(X @ W_in + b); x0 = x. K=128, MFMA (unchanged) ----
__global__ void __launch_bounds__(256) mm_in_mfma(const float* __restrict__ A,
    const _Float16* __restrict__ wbuf, const float* __restrict__ b,
    float* __restrict__ C, float* __restrict__ C2, int ntiles) {
  int l = threadIdx.x & 63, q = l >> 4, m16 = l & 15;
  int wid = (blockIdx.x * blockDim.x + threadIdx.x) >> 6;
  int nw = (gridDim.x * blockDim.x) >> 6;
  const h8* wf = (const h8*)(wbuf + OFF_IN);
  h8 w[16];
#pragma unroll
  for (int f = 0; f < 16; ++f) w[f] = wf[f * 64 + l];
  float bv[4];
#pragma unroll
  for (int jt = 0; jt < 4; ++jt) bv[jt] = b[jt * 16 + m16];
  for (int t = wid; t < ntiles; t += nw) {
    int rbase = t * 16;
    const float* rp = A + (size_t)(rbase + m16) * 128 + q * 8;
    h8 a0 = ld_a32(rp), a1 = ld_a32(rp + 32), a2 = ld_a32(rp + 64), a3 = ld_a32(rp + 96);
    f4 acc[4];
#pragma unroll
    for (int jt = 0; jt < 4; ++jt) {
      acc[jt] = zero4();
      acc[jt] = MFMA(a0, w[jt * 4 + 0], acc[jt]);
      acc[jt] = MFMA(a1, w[jt * 4 + 1], acc[jt]);
      acc[jt] = MFMA(a2, w[jt * 4 + 2], acc[jt]);
      acc[jt] = MFMA(a3, w[jt * 4 + 3], acc[jt]);
    }
#pragma unroll
    for (int jt = 0; jt < 4; ++jt)
#pragma unroll
      for (int r = 0; r < 4; ++r) {
        float v = fmaxf(acc[jt][r] + bv[jt], 0.0f);
        size_t idx = (size_t)(rbase + q * 4 + r) * 64 + jt * 16 + m16;
        C[idx] = v; C2[idx] = v;
      }
  }
}

// ---- h = relu(x@W1a+b1a)@W1b + b1b  (fp16 out), MFMA + LDS transpose (unchanged) ----
__global__ void __launch_bounds__(256) mm_dual_mfma(const float* __restrict__ x,
    const _Float16* __restrict__ wbuf, const float* __restrict__ b1a,
    const float* __restrict__ b1b, __half* __restrict__ h, int ntiles) {
  __shared__ float lds[4][16 * 68];
  int l = threadIdx.x & 63, q = l >> 4, m16 = l & 15, wv = threadIdx.x >> 6;
  int wid = (blockIdx.x * blockDim.x + threadIdx.x) >> 6;
  int nw = (gridDim.x * blockDim.x) >> 6;
  const h8* wap = (const h8*)(wbuf + OFF_1A);
  const h8* wbp = (const h8*)(wbuf + OFF_1B);
  h8 wa[8], wb[8];
#pragma unroll
  for (int f = 0; f < 8; ++f) { wa[f] = wap[f * 64 + l]; wb[f] = wbp[f * 64 + l]; }
  float bav[4], bbv[4];
#pragma unroll
  for (int jt = 0; jt < 4; ++jt) { bav[jt] = b1a[jt * 16 + m16]; bbv[jt] = b1b[jt * 16 + m16]; }
  float* myl = lds[wv];
  for (int t = wid; t < ntiles; t += nw) {
    int rbase = t * 16;
    const float* rp = x + (size_t)(rbase + m16) * 64 + q * 8;
    h8 a0 = ld_a32(rp), a1 = ld_a32(rp + 32);
    f4 acc[4];
#pragma unroll
    for (int jt = 0; jt < 4; ++jt) {
      acc[jt] = zero4();
      acc[jt] = MFMA(a0, wa[jt * 2 + 0], acc[jt]);
      acc[jt] = MFMA(a1, wa[jt * 2 + 1], acc[jt]);
    }
#pragma unroll
    for (int jt = 0; jt < 4; ++jt)
#pragma unroll
      for (int r = 0; r < 4; ++r)
        myl[(q * 4 + r) * 68 + jt * 16 + m16] = fmaxf(acc[jt][r] + bav[jt], 0.0f);
    h8 t0, t1;
#pragma unroll
    for (int j = 0; j < 8; ++j) t0[j] = (_Float16)myl[m16 * 68 + q * 8 + j];
#pragma unroll
    for (int j = 0; j < 8; ++j) t1[j] = (_Float16)myl[m16 * 68 + 32 + q * 8 + j];
#pragma unroll
    for (int jt = 0; jt < 4; ++jt) {
      acc[jt] = zero4();
      acc[jt] = MFMA(t0, wb[jt * 2 + 0], acc[jt]);
      acc[jt] = MFMA(t1, wb[jt * 2 + 1], acc[jt]);
    }
#pragma unroll
    for (int jt = 0; jt < 4; ++jt)
#pragma unroll
      for (int r = 0; r < 4; ++r)
        h[(size_t)(rbase + q * 4 + r) * 64 + jt * 16 + m16] = __float2half(acc[jt][r] + bbv[jt]);
  }
}

// ---- V->E pull: wave per edge; lane (g,c) loads 16B of row csr[i+g] ----
// one VMEM instr = 8 rows = 1KB; shfl_xor(8,16,32) tree; lanes g==0 store row.
__global__ void __launch_bounds__(256) ve_pull_k(const __half* __restrict__ h,
    const int* __restrict__ csr, const int* __restrict__ off, const int* __restrict__ cnt,
    const float* __restrict__ invE, __half* __restrict__ Xe, int e) {
  int lane = threadIdx.x & 63;
  int w = (blockIdx.x * blockDim.x + threadIdx.x) >> 6;
  if (w >= e) return;
  int lo = off[w], end = lo + cnt[w];
  int g = lane >> 3, c = lane & 7;
  float acc[8];
#pragma unroll
  for (int j = 0; j < 8; ++j) acc[j] = 0.0f;
  for (int i = lo + g; i < end; i += 8) {
    int r = csr[i];
    h8 v = *(const h8*)(h + (size_t)r * 64 + c * 8);
#pragma unroll
    for (int j = 0; j < 8; ++j) acc[j] += (float)v[j];
  }
#pragma unroll
  for (int j = 0; j < 8; ++j) {
    acc[j] += __shfl_xor(acc[j], 8);
    acc[j] += __shfl_xor(acc[j], 16);
    acc[j] += __shfl_xor(acc[j], 32);
  }
  if (g == 0) {
    float s = invE[w];
    h8 o;
#pragma unroll
    for (int j = 0; j < 8; ++j) o[j] = (_Float16)(acc[j] * s);
    *(h8*)(Xe + (size_t)w * 64 + c * 8) = o;
  }
}

// ---- E->V pull: wave per node, same 8-rows-per-instr structure ----
__global__ void __launch_bounds__(256) zgather_k(const __half* __restrict__ Xe,
    const int* __restrict__ dstArr, const int* __restrict__ roff,
    __half* __restrict__ z, int n) {
  int lane = threadIdx.x & 63;
  int w = (blockIdx.x * blockDim.x + threadIdx.x) >> 6;
  if (w >= n) return;
  int lo = roff[w], hi = roff[w + 1];
  int g = lane >> 3, c = lane & 7;
  float acc[8];
#pragma unroll
  for (int j = 0; j < 8; ++j) acc[j] = 0.0f;
  for (int i = lo + g; i < hi; i += 8) {
    int r = dstArr[i];
    h8 v = *(const h8*)(Xe + (size_t)r * 64 + c * 8);
#pragma unroll
    for (int j = 0; j < 8; ++j) acc[j] += (float)v[j];
  }
#pragma unroll
  for (int j = 0; j < 8; ++j) {
    acc[j] += __shfl_xor(acc[j], 8);
    acc[j] += __shfl_xor(acc[j], 16);
    acc[j] += __shfl_xor(acc[j], 32);
  }
  if (g == 0) {
    float s = (hi > lo) ? 1.0f / (float)(hi - lo) : 0.0f;
    h8 o;
#pragma unroll
    for (int j = 0; j < 8; ++j) o[j] = (_Float16)(acc[j] * s);
    *(h8*)(z + (size_t)w * 64 + c * 8) = o;
  }
}

// ---- fused: res = 0.5*x0 + mask*0.5*(cat(x,z)@W2+b2); x = relu(res@W3+b3). MFMA (unchanged) ----
__global__ void __launch_bounds__(256) catmm_w3_mfma(float* __restrict__ x,
    const __half* __restrict__ z, const float* __restrict__ x0,
    const int* __restrict__ roff, const _Float16* __restrict__ wbuf,
    const float* __restrict__ b2, const float* __restrict__ b3, int ntiles) {
  __shared__ float lds[4][16 * 68];
  int l = threadIdx.x & 63, q = l >> 4, m16 = l & 15, wv = threadIdx.x >> 6;
  int wid = (blockIdx.x * blockDim.x + threadIdx.x) >> 6;
  int nw = (gridDim.x * blockDim.x) >> 6;
  const h8* w2p = (const h8*)(wbuf + OFF_W2);
  const h8* w3p = (const h8*)(wbuf + OFF_W3);
  h8 w2[16], w3[8];
#pragma unroll
  for (int f = 0; f < 16; ++f) w2[f] = w2p[f * 64 + l];
#pragma unroll
  for (int f = 0; f < 8; ++f) w3[f] = w3p[f * 64 + l];
  float bv2[4], bv3[4];
#pragma unroll
  for (int jt = 0; jt < 4; ++jt) { bv2[jt] = b2[jt * 16 + m16]; bv3[jt] = b3[jt * 16 + m16]; }
  float* myl = lds[wv];
  for (int t = wid; t < ntiles; t += nw) {
    int rbase = t * 16;
    const float* rp = x + (size_t)(rbase + m16) * 64 + q * 8;
    h8 a0 = ld_a32(rp), a1 = ld_a32(rp + 32);
    const h8* zp = (const h8*)(z + (size_t)(rbase + m16) * 64 + q * 8);
    h8 az0 = zp[0], az1 = zp[2];
    f4 acc[4];
#pragma unroll
    for (int jt = 0; jt < 4; ++jt) {
      acc[jt] = zero4();
      acc[jt] = MFMA(a0,  w2[jt * 4 + 0], acc[jt]);
      acc[jt] = MFMA(a1,  w2[jt * 4 + 1], acc[jt]);
      acc[jt] = MFMA(az0, w2[jt * 4 + 2], acc[jt]);
      acc[jt] = MFMA(az1, w2[jt * 4 + 3], acc[jt]);
    }
#pragma unroll
    for (int r = 0; r < 4; ++r) {
      int row = rbase + q * 4 + r;
      float msk = (roff[row + 1] > roff[row]) ? 0.5f : 0.0f;
#pragma unroll
      for (int jt = 0; jt < 4; ++jt) {
        float val = acc[jt][r] + bv2[jt];
        float res = fmaf(msk, val, 0.5f * x0[(size_t)row * 64 + jt * 16 + m16]);
        myl[(q * 4 + r) * 68 + jt * 16 + m16] = res;
      }
    }
    h8 t0, t1;
#pragma unroll
    for (int j = 0; j < 8; ++j) t0[j] = (_Float16)myl[m16 * 68 + q * 8 + j];
#pragma unroll
    for (int j = 0; j < 8; ++j) t1[j] = (_Float16)myl[m16 * 68 + 32 + q * 8 + j];
#pragma unroll
    for (int jt = 0; jt < 4; ++jt) {
      acc[jt] = zero4();
      acc[jt] = MFMA(t0, w3[jt * 2 + 0], acc[jt]);
      acc[jt] = MFMA(t1, w3[jt * 2 + 1], acc[jt]);
    }
#pragma unroll
    for (int jt = 0; jt < 4; ++jt)
#pragma unroll
      for (int r = 0; r < 4; ++r)
        x[(size_t)(rbase + q * 4 + r) * 64 + jt * 16 + m16] = fmaxf(acc[jt][r] + bv3[jt], 0.0f);
  }
}

// ---- classifier (unchanged) ----
__global__ void __launch_bounds__(256) classifier_mfma(const float* __restrict__ x,
    const _Float16* __restrict__ wbuf, const float* __restrict__ bc1,
    const float* __restrict__ bc2, float* __restrict__ out, int ntiles) {
  __shared__ float lds[4][16 * 68];
  int l = threadIdx.x & 63, q = l >> 4, m16 = l & 15, wv = threadIdx.x >> 6;
  int wid = (blockIdx.x * blockDim.x + threadIdx.x) >> 6;
  int nw = (gridDim.x * blockDim.x) >> 6;
  const h8* w1p = (const h8*)(wbuf + OFF_C1);
  const h8* w2p = (const h8*)(wbuf + OFF_C2);
  h8 w1[8], w2[4];
#pragma unroll
  for (int f = 0; f < 8; ++f) w1[f] = w1p[f * 64 + l];
#pragma unroll
  for (int f = 0; f < 4; ++f) w2[f] = w2p[f * 64 + l];
  float bv1[4], bv2[2];
#pragma unroll
  for (int jt = 0; jt < 4; ++jt) bv1[jt] = bc1[jt * 16 + m16];
#pragma unroll
  for (int jt = 0; jt < 2; ++jt) bv2[jt] = bc2[jt * 16 + m16];
  float* myl = lds[wv];
  for (int t = wid; t < ntiles; t += nw) {
    int rbase = t * 16;
    const float* rp = x + (size_t)(rbase + m16) * 64 + q * 8;
    h8 a0 = ld_a32(rp), a1 = ld_a32(rp + 32);
    f4 acc[4];
#pragma unroll
    for (int jt = 0; jt < 4; ++jt) {
      acc[jt] = zero4();
      acc[jt] = MFMA(a0, w1[jt * 2 + 0], acc[jt]);
      acc[jt] = MFMA(a1, w1[jt * 2 + 1], acc[jt]);
    }
#pragma unroll
    for (int jt = 0; jt < 4; ++jt)
#pragma unroll
      for (int r = 0; r < 4; ++r)
        myl[(q * 4 + r) * 68 + jt * 16 + m16] = fmaxf(acc[jt][r] + bv1[jt], 0.0f);
    h8 t0, t1;
#pragma unroll
    for (int j = 0; j < 8; ++j) t0[j] = (_Float16)myl[m16 * 68 + q * 8 + j];
#pragma unroll
    for (int j = 0; j < 8; ++j) t1[j] = (_Float16)myl[m16 * 68 + 32 + q * 8 + j];
    f4 o[2];
#pragma unroll
    for (int jt = 0; jt < 2; ++jt) {
      o[jt] = zero4();
      o[jt] = MFMA(t0, w2[jt * 2 + 0], o[jt]);
      o[jt] = MFMA(t1, w2[jt * 2 + 1], o[jt]);
    }
#pragma unroll
    for (int jt = 0; jt < 2; ++jt)
#pragma unroll
      for (int r = 0; r < 4; ++r)
        out[(size_t)(rbase + q * 4 + r) * 32 + jt * 16 + m16] = o[jt][r] + bv2[jt];
  }
}

// ---- per-graph mean readout (unchanged) ----
__global__ void __launch_bounds__(256) readout_k(const float* __restrict__ xc,
    const int* __restrict__ batch, int n, float* __restrict__ out) {
  __shared__ float part[8][32];
  int g = blockIdx.x;
  int lo = lbound(batch, n, g);
  int hi = lbound(batch, n, g + 1);
  int j = threadIdx.x & 31, r = threadIdx.x >> 5;
  float acc = 0.0f;
  for (int i = lo + r; i < hi; i += 8) acc += xc[(size_t)i * 32 + j];
  part[r][j] = acc;
  __syncthreads();
  if (threadIdx.x < 32) {
    float s = 0.0f;
#pragma unroll
    for (int rr = 0; rr < 8; ++rr) s += part[rr][j];
    out[g * 32 + j] = (hi > lo) ? s / (float)(hi - lo) : 0.0f;
  }
}

extern "C" void kernel_launch(void* const* d_in, const int* in_sizes, int n_in,
                              void* d_out, int out_size, void* d_ws, size_t ws_size,
                              hipStream_t stream) {
  const float* X    = (const float*)d_in[0];
  const int*   src  = (const int*)d_in[1];
  const int*   dst  = (const int*)d_in[2];
  const int*   batch= (const int*)d_in[3];
  const float* W_in = (const float*)d_in[4];
  const float* b_in = (const float*)d_in[5];
  const float* W1a  = (const float*)d_in[6];
  const float* b1a  = (const float*)d_in[7];
  const float* W1b  = (const float*)d_in[8];
  const float* b1b  = (const float*)d_in[9];
  const float* W2   = (const float*)d_in[10];
  const float* b2   = (const float*)d_in[11];
  const float* W3   = (const float*)d_in[12];
  const float* b3   = (const float*)d_in[13];
  const float* Wc1  = (const float*)d_in[14];
  const float* bc1  = (const float*)d_in[15];
  const float* Wc2  = (const float*)d_in[16];
  const float* bc2  = (const float*)d_in[17];
  float* out = (float*)d_out;

  // workspace layout (~77 MB)
  float* p  = (float*)d_ws;
  float* x  = p; p += (size_t)NN * 64;            // 25.6 MB
  float* x0 = p; p += (size_t)NN * 64;            // 25.6 MB (aliased as classifier out later)
  __half* hz = (__half*)p; p += (size_t)NN * 32;  // 12.8 MB: h then z
  __half* Xe = (__half*)p; p += (size_t)NE * 32;  // 6.4 MB
  float* invE = p; p += NE;
  _Float16* wbuf = (_Float16*)p; p += WBUF_HALVES / 2 + 16;
  int* q     = (int*)p;
  int* cnt   = q; q += NE;
  int* off   = q; q += NE;
  int* cursor= q; q += NE;
  int* roff  = q; q += NN + 1;
  int* csr   = q; q += NZ;                        // 5.12 MB
  int* bsum  = q; q += 256;
  __half* h = hz;
  __half* z = hz;           // alias: h fully consumed by ve_pull before zgather writes z
  float* outc = x0;         // alias: x0 dead after last catmm_w3

  // CSR-by-dst + row offsets + weight prep (once per call)
  hipMemsetAsync(cnt, 0, (size_t)NE * sizeof(int), stream);
  count_k<<<(NZ + 255) / 256, 256, 0, stream>>>(dst, cnt, NZ);
  bsum_k<<<NB, 256, 0, stream>>>(cnt, bsum, NE);
  bscan_k<<<1, 256, 0, stream>>>(bsum, NB);
  csroff_k<<<NB, 256, 0, stream>>>(cnt, bsum, off, cursor, invE, NE);
  fill_k<<<(NZ + 255) / 256, 256, 0, stream>>>(src, dst, cursor, csr, NZ);
  rowoff_diff_k<<<(NZ + 255) / 256, 256, 0, stream>>>(src, roff, NN, NZ);
  prep_w_k<<<68, 64, 0, stream>>>(W_in, W1a, W1b, W2, W3, Wc1, Wc2, wbuf);

  mm_in_mfma<<<1563, 256, 0, stream>>>(X, wbuf, b_in, x, x0, NTILE);

  for (int l = 0; l < 2; ++l) {
    mm_dual_mfma<<<1563, 256, 0, stream>>>(x, wbuf, b1a, b1b, h, NTILE);
    ve_pull_k<<<(NE + 3) / 4, 256, 0, stream>>>(h, csr, off, cnt, invE, Xe, NE);
    zgather_k<<<(NN + 3) / 4, 256, 0, stream>>>(Xe, dst, roff, z, NN);
    catmm_w3_mfma<<<1563, 256, 0, stream>>>(x, z, x0, roff, wbuf, b2, b3, NTILE);
  }

  classifier_mfma<<<1563, 256, 0, stream>>>(x, wbuf, bc1, bc2, outc, NTILE);
  readout_k<<<NG, 256, 0, stream>>>(outc, batch, NN, out);
}

// Round 8
// 482.631 us; speedup vs baseline: 1.8161x; 1.0952x over previous
//
#include <hip/hip_runtime.h>
#include <hip/hip_fp16.h>

// EquivSetGNN forward, MI355X.
// R8: fill_k (95us, 84MB WRITE for 5MB payload — 16x line-allocation amplification
// on random 4B scatter) replaced by two-pass LDS-staged binned scatter:
//   A) coarse-bin by dst>>8 into packed words ((dst&255)<<24 | src), run-writes;
//   B) one block per bucket: LDS exact-position scatter + coalesced copy-out.
// Build traffic 92MB -> ~26MB coalesced. Everything else unchanged from R7.

constexpr int NN = 100000;   // nodes
constexpr int NE = 50000;    // hyperedges
constexpr int NZ = 1280000;  // incidences
constexpr int NG = 256;      // graphs
constexpr int NB = (NE + 255) / 256;
constexpr int NTILE = NN / 16;  // 6250 row-tiles of 16
constexpr int CB = 196;         // coarse buckets = ceil(NE/256)
constexpr int CHUNK = 4000;
constexpr int NBLK_A = NZ / CHUNK;  // 320

typedef _Float16 h8 __attribute__((ext_vector_type(8)));
typedef float f4 __attribute__((ext_vector_type(4)));

constexpr int OFF_IN  = 0;
constexpr int OFF_1A  = 8192;
constexpr int OFF_1B  = 12288;
constexpr int OFF_W2  = 16384;
constexpr int OFF_W3  = 24576;
constexpr int OFF_C1  = 28672;
constexpr int OFF_C2  = 32768;
constexpr int WBUF_HALVES = 34816;

__device__ __forceinline__ int lbound(const int* a, int n, int v) {
  int lo = 0, hi = n;
  while (lo < hi) { int m = (lo + hi) >> 1; if (a[m] < v) lo = m + 1; else hi = m; }
  return lo;
}

__device__ __forceinline__ f4 zero4() { f4 z; z[0]=0.f; z[1]=0.f; z[2]=0.f; z[3]=0.f; return z; }

__device__ __forceinline__ h8 ld_a32(const float* p) {
  const f4* v = (const f4*)p;
  f4 lo = v[0], hi = v[1];
  h8 r;
  r[0]=(_Float16)lo[0]; r[1]=(_Float16)lo[1]; r[2]=(_Float16)lo[2]; r[3]=(_Float16)lo[3];
  r[4]=(_Float16)hi[0]; r[5]=(_Float16)hi[1]; r[6]=(_Float16)hi[2]; r[7]=(_Float16)hi[3];
  return r;
}

#define MFMA(a, b, c) __builtin_amdgcn_mfma_f32_16x16x32_f16((a), (b), (c), 0, 0, 0)

// ---- CSR-by-dst build ----
__global__ void count_k(const int* __restrict__ dst, int* __restrict__ cnt, int nnz) {
  int i = blockIdx.x * blockDim.x + threadIdx.x;
  if (i < nnz) atomicAdd(&cnt[dst[i]], 1);
}

__global__ void bsum_k(const int* __restrict__ cnt, int* __restrict__ bsum, int e) {
  __shared__ int red[256];
  int i = blockIdx.x * 256 + threadIdx.x;
  red[threadIdx.x] = (i < e) ? cnt[i] : 0;
  __syncthreads();
  for (int s = 128; s > 0; s >>= 1) {
    if (threadIdx.x < s) red[threadIdx.x] += red[threadIdx.x + s];
    __syncthreads();
  }
  if (threadIdx.x == 0) bsum[blockIdx.x] = red[0];
}

__global__ void bscan_k(int* __restrict__ bsum, int nb) {
  __shared__ int sh[256];
  int t = threadIdx.x;
  int my = (t < nb) ? bsum[t] : 0;
  sh[t] = my;
  __syncthreads();
  for (int ofs = 1; ofs < 256; ofs <<= 1) {
    int v = (t >= ofs) ? sh[t - ofs] : 0;
    __syncthreads();
    sh[t] += v;
    __syncthreads();
  }
  if (t < nb) bsum[t] = sh[t] - my;
}

__global__ void csroff_k(const int* __restrict__ cnt, const int* __restrict__ bsum,
                         int* __restrict__ off, float* __restrict__ invE, int e) {
  __shared__ int sh[256];
  int t = threadIdx.x;
  int i = blockIdx.x * 256 + t;
  int c = (i < e) ? cnt[i] : 0;
  sh[t] = c;
  __syncthreads();
  for (int ofs = 1; ofs < 256; ofs <<= 1) {
    int v = (t >= ofs) ? sh[t - ofs] : 0;
    __syncthreads();
    sh[t] += v;
    __syncthreads();
  }
  int excl = sh[t] - c + bsum[blockIdx.x];
  if (i < e) {
    off[i] = excl;
    invE[i] = 1.0f / (float)max(c, 1);
  }
}

__global__ void initcc_k(const int* __restrict__ off, int* __restrict__ cc) {
  int b = threadIdx.x + blockIdx.x * blockDim.x;
  if (b < CB) cc[b] = off[b << 8];
}

// Pass A: coarse bin into packed words ((dst&255)<<24 | src)
__global__ void __launch_bounds__(256) binA_k(const int* __restrict__ src,
    const int* __restrict__ dst, int* __restrict__ cc, unsigned int* __restrict__ words) {
  __shared__ int cnt[CB];
  __shared__ int base[CB];
  int t = threadIdx.x;
  int start = blockIdx.x * CHUNK;
  for (int i = t; i < CB; i += 256) cnt[i] = 0;
  __syncthreads();
  for (int i = start + t; i < start + CHUNK; i += 256)
    atomicAdd(&cnt[dst[i] >> 8], 1);
  __syncthreads();
  for (int i = t; i < CB; i += 256) base[i] = atomicAdd(&cc[i], cnt[i]);
  __syncthreads();
  for (int i = t; i < CB; i += 256) cnt[i] = 0;  // reuse as cursor
  __syncthreads();
  for (int i = start + t; i < start + CHUNK; i += 256) {
    int d = dst[i];
    int b = d >> 8;
    int p = base[b] + atomicAdd(&cnt[b], 1);
    words[p] = (unsigned)src[i] | ((unsigned)(d & 255) << 24);
  }
}

// Pass B: exact scatter within bucket via LDS staging, coalesced copy-out
__global__ void __launch_bounds__(256) binB_k(const unsigned int* __restrict__ words,
    const int* __restrict__ off, int* __restrict__ csr, int ne, int nnz) {
  __shared__ int buf[8192];
  __shared__ int cur[256];
  int b = blockIdx.x, t = threadIdx.x;
  int e0 = b << 8;
  int ecnt = min(256, ne - e0);
  int gbase = off[e0];
  int gend = (e0 + 256 >= ne) ? nnz : off[e0 + 256];
  cur[t] = (t < ecnt) ? (off[e0 + t] - gbase) : 0;
  __syncthreads();
  int cntb = gend - gbase;
  for (int i = t; i < cntb; i += 256) {
    unsigned w = words[gbase + i];
    int s = (int)(w & 0xFFFFFFu);
    int le = (int)(w >> 24);
    int p = atomicAdd(&cur[le], 1);
    if (p < 8192) buf[p] = s;
    else csr[gbase + p] = s;  // statistically never (bucket ~6554 +- 81)
  }
  __syncthreads();
  int lim = min(cntb, 8192);
  for (int i = t; i < lim; i += 256) csr[gbase + i] = buf[i];
}

__global__ void rowoff_diff_k(const int* __restrict__ src, int* __restrict__ roff,
                              int n, int nnz) {
  int i = blockIdx.x * blockDim.x + threadIdx.x;
  if (i >= nnz) return;
  int s = src[i];
  int prev = (i == 0) ? -1 : src[i - 1];
  for (int v = prev + 1; v <= s; ++v) roff[v] = i;
  if (i == nnz - 1) {
    for (int v = s + 1; v <= n; ++v) roff[v] = nnz;
  }
}

// ---- weight prep (unchanged) ----
__global__ void prep_w_k(const float* __restrict__ W_in, const float* __restrict__ W1a,
                         const float* __restrict__ W1b, const float* __restrict__ W2,
                         const float* __restrict__ W3,  const float* __restrict__ Wc1,
                         const float* __restrict__ Wc2, _Float16* __restrict__ wbuf) {
  int b = blockIdx.x, l = threadIdx.x;
  const float* src; int K, J; _Float16* dst; int tile;
  if      (b < 16) { src = W_in; K = 128; J = 64; dst = wbuf + OFF_IN; tile = b; }
  else if (b < 24) { src = W1a;  K = 64;  J = 64; dst = wbuf + OFF_1A; tile = b - 16; }
  else if (b < 32) { src = W1b;  K = 64;  J = 64; dst = wbuf + OFF_1B; tile = b - 24; }
  else if (b < 48) { src = W2;   K = 128; J = 64; dst = wbuf + OFF_W2; tile = b - 32; }
  else if (b < 56) { src = W3;   K = 64;  J = 64; dst = wbuf + OFF_W3; tile = b - 48; }
  else if (b < 64) { src = Wc1;  K = 64;  J = 64; dst = wbuf + OFF_C1; tile = b - 56; }
  else             { src = Wc2;  K = 64;  J = 32; dst = wbuf + OFF_C2; tile = b - 64; }
  int KS = K / 32;
  int jt = tile / KS, ks = tile % KS;
  int q = l >> 4, m = l & 15;
#pragma unroll
  for (int j = 0; j < 8; ++j)
    dst[((size_t)tile * 64 + l) * 8 + j] =
        (_Float16)src[(size_t)(ks * 32 + q * 8 + j) * J + jt * 16 + m];
}

// ---- x = relu(X @ W_in + b); x0 = x. (unchanged) ----
__global__ void __launch_bounds__(256) mm_in_mfma(const float* __restrict__ A,
    const _Float16* __restrict__ wbuf, const float* __restrict__ b,
    float* __restrict__ C, float* __restrict__ C2, int ntiles) {
  int l = threadIdx.x & 63, q = l >> 4, m16 = l & 15;
  int wid = (blockIdx.x * blockDim.x + threadIdx.x) >> 6;
  int nw = (gridDim.x * blockDim.x) >> 6;
  const h8* wf = (const h8*)(wbuf + OFF_IN);
  h8 w[16];
#pragma unroll
  for (int f = 0; f < 16; ++f) w[f] = wf[f * 64 + l];
  float bv[4];
#pragma unroll
  for (int jt = 0; jt < 4; ++jt) bv[jt] = b[jt * 16 + m16];
  for (int t = wid; t < ntiles; t += nw) {
    int rbase = t * 16;
    const float* rp = A + (size_t)(rbase + m16) * 128 + q * 8;
    h8 a0 = ld_a32(rp), a1 = ld_a32(rp + 32), a2 = ld_a32(rp + 64), a3 = ld_a32(rp + 96);
    f4 acc[4];
#pragma unroll
    for (int jt = 0; jt < 4; ++jt) {
      acc[jt] = zero4();
      acc[jt] = MFMA(a0, w[jt * 4 + 0], acc[jt]);
      acc[jt] = MFMA(a1, w[jt * 4 + 1], acc[jt]);
      acc[jt] = MFMA(a2, w[jt * 4 + 2], acc[jt]);
      acc[jt] = MFMA(a3, w[jt * 4 + 3], acc[jt]);
    }
#pragma unroll
    for (int jt = 0; jt < 4; ++jt)
#pragma unroll
      for (int r = 0; r < 4; ++r) {
        float v = fmaxf(acc[jt][r] + bv[jt], 0.0f);
        size_t idx = (size_t)(rbase + q * 4 + r) * 64 + jt * 16 + m16;
        C[idx] = v; C2[idx] = v;
      }
  }
}

// ---- h = relu(x@W1a+b1a)@W1b + b1b (unchanged) ----
__global__ void __launch_bounds__(256) mm_dual_mfma(const float* __restrict__ x,
    const _Float16* __restrict__ wbuf, const float* __restrict__ b1a,
    const float* __restrict__ b1b, __half* __restrict__ h, int ntiles) {
  __shared__ float lds[4][16 * 68];
  int l = threadIdx.x & 63, q = l >> 4, m16 = l & 15, wv = threadIdx.x >> 6;
  int wid = (blockIdx.x * blockDim.x + threadIdx.x) >> 6;
  int nw = (gridDim.x * blockDim.x) >> 6;
  const h8* wap = (const h8*)(wbuf + OFF_1A);
  const h8* wbp = (const h8*)(wbuf + OFF_1B);
  h8 wa[8], wb[8];
#pragma unroll
  for (int f = 0; f < 8; ++f) { wa[f] = wap[f * 64 + l]; wb[f] = wbp[f * 64 + l]; }
  float bav[4], bbv[4];
#pragma unroll
  for (int jt = 0; jt < 4; ++jt) { bav[jt] = b1a[jt * 16 + m16]; bbv[jt] = b1b[jt * 16 + m16]; }
  float* myl = lds[wv];
  for (int t = wid; t < ntiles; t += nw) {
    int rbase = t * 16;
    const float* rp = x + (size_t)(rbase + m16) * 64 + q * 8;
    h8 a0 = ld_a32(rp), a1 = ld_a32(rp + 32);
    f4 acc[4];
#pragma unroll
    for (int jt = 0; jt < 4; ++jt) {
      acc[jt] = zero4();
      acc[jt] = MFMA(a0, wa[jt * 2 + 0], acc[jt]);
      acc[jt] = MFMA(a1, wa[jt * 2 + 1], acc[jt]);
    }
#pragma unroll
    for (int jt = 0; jt < 4; ++jt)
#pragma unroll
      for (int r = 0; r < 4; ++r)
        myl[(q * 4 + r) * 68 + jt * 16 + m16] = fmaxf(acc[jt][r] + bav[jt], 0.0f);
    h8 t0, t1;
#pragma unroll
    for (int j = 0; j < 8; ++j) t0[j] = (_Float16)myl[m16 * 68 + q * 8 + j];
#pragma unroll
    for (int j = 0; j < 8; ++j) t1[j] = (_Float16)myl[m16 * 68 + 32 + q * 8 + j];
#pragma unroll
    for (int jt = 0; jt < 4; ++jt) {
      acc[jt] = zero4();
      acc[jt] = MFMA(t0, wb[jt * 2 + 0], acc[jt]);
      acc[jt] = MFMA(t1, wb[jt * 2 + 1], acc[jt]);
    }
#pragma unroll
    for (int jt = 0; jt < 4; ++jt)
#pragma unroll
      for (int r = 0; r < 4; ++r)
        h[(size_t)(rbase + q * 4 + r) * 64 + jt * 16 + m16] = __float2half(acc[jt][r] + bbv[jt]);
  }
}

// ---- V->E pull (unchanged from R7) ----
__global__ void __launch_bounds__(256) ve_pull_k(const __half* __restrict__ h,
    const int* __restrict__ csr, const int* __restrict__ off, const int* __restrict__ cnt,
    const float* __restrict__ invE, __half* __restrict__ Xe, int e) {
  int lane = threadIdx.x & 63;
  int w = (blockIdx.x * blockDim.x + threadIdx.x) >> 6;
  if (w >= e) return;
  int lo = off[w], end = lo + cnt[w];
  int g = lane >> 3, c = lane & 7;
  float acc[8];
#pragma unroll
  for (int j = 0; j < 8; ++j) acc[j] = 0.0f;
  for (int i = lo + g; i < end; i += 8) {
    int r = csr[i];
    h8 v = *(const h8*)(h + (size_t)r * 64 + c * 8);
#pragma unroll
    for (int j = 0; j < 8; ++j) acc[j] += (float)v[j];
  }
#pragma unroll
  for (int j = 0; j < 8; ++j) {
    acc[j] += __shfl_xor(acc[j], 8);
    acc[j] += __shfl_xor(acc[j], 16);
    acc[j] += __shfl_xor(acc[j], 32);
  }
  if (g == 0) {
    float s = invE[w];
    h8 o;
#pragma unroll
    for (int j = 0; j < 8; ++j) o[j] = (_Float16)(acc[j] * s);
    *(h8*)(Xe + (size_t)w * 64 + c * 8) = o;
  }
}

// ---- E->V pull (unchanged from R7) ----
__global__ void __launch_bounds__(256) zgather_k(const __half* __restrict__ Xe,
    const int* __restrict__ dstArr, const int* __restrict__ roff,
    __half* __restrict__ z, int n) {
  int lane = threadIdx.x & 63;
  int w = (blockIdx.x * blockDim.x + threadIdx.x) >> 6;
  if (w >= n) return;
  int lo = roff[w], hi = roff[w + 1];
  int g = lane >> 3, c = lane & 7;
  float acc[8];
#pragma unroll
  for (int j = 0; j < 8; ++j) acc[j] = 0.0f;
  for (int i = lo + g; i < hi; i += 8) {
    int r = dstArr[i];
    h8 v = *(const h8*)(Xe + (size_t)r * 64 + c * 8);
#pragma unroll
    for (int j = 0; j < 8; ++j) acc[j] += (float)v[j];
  }
#pragma unroll
  for (int j = 0; j < 8; ++j) {
    acc[j] += __shfl_xor(acc[j], 8);
    acc[j] += __shfl_xor(acc[j], 16);
    acc[j] += __shfl_xor(acc[j], 32);
  }
  if (g == 0) {
    float s = (hi > lo) ? 1.0f / (float)(hi - lo) : 0.0f;
    h8 o;
#pragma unroll
    for (int j = 0; j < 8; ++j) o[j] = (_Float16)(acc[j] * s);
    *(h8*)(z + (size_t)w * 64 + c * 8) = o;
  }
}

// ---- catmm + W3 (unchanged) ----
__global__ void __launch_bounds__(256) catmm_w3_mfma(float* __restrict__ x,
    const __half* __restrict__ z, const float* __restrict__ x0,
    const int* __restrict__ roff, const _Float16* __restrict__ wbuf,
    const float* __restrict__ b2, const float* __restrict__ b3, int ntiles) {
  __shared__ float lds[4][16 * 68];
  int l = threadIdx.x & 63, q = l >> 4, m16 = l & 15, wv = threadIdx.x >> 6;
  int wid = (blockIdx.x * blockDim.x + threadIdx.x) >> 6;
  int nw = (gridDim.x * blockDim.x) >> 6;
  const h8* w2p = (const h8*)(wbuf + OFF_W2);
  const h8* w3p = (const h8*)(wbuf + OFF_W3);
  h8 w2[16], w3[8];
#pragma unroll
  for (int f = 0; f < 16; ++f) w2[f] = w2p[f * 64 + l];
#pragma unroll
  for (int f = 0; f < 8; ++f) w3[f] = w3p[f * 64 + l];
  float bv2[4], bv3[4];
#pragma unroll
  for (int jt = 0; jt < 4; ++jt) { bv2[jt] = b2[jt * 16 + m16]; bv3[jt] = b3[jt * 16 + m16]; }
  float* myl = lds[wv];
  for (int t = wid; t < ntiles; t += nw) {
    int rbase = t * 16;
    const float* rp = x + (size_t)(rbase + m16) * 64 + q * 8;
    h8 a0 = ld_a32(rp), a1 = ld_a32(rp + 32);
    const h8* zp = (const h8*)(z + (size_t)(rbase + m16) * 64 + q * 8);
    h8 az0 = zp[0], az1 = zp[2];
    f4 acc[4];
#pragma unroll
    for (int jt = 0; jt < 4; ++jt) {
      acc[jt] = zero4();
      acc[jt] = MFMA(a0,  w2[jt * 4 + 0], acc[jt]);
      acc[jt] = MFMA(a1,  w2[jt * 4 + 1], acc[jt]);
      acc[jt] = MFMA(az0, w2[jt * 4 + 2], acc[jt]);
      acc[jt] = MFMA(az1, w2[jt * 4 + 3], acc[jt]);
    }
#pragma unroll
    for (int r = 0; r < 4; ++r) {
      int row = rbase + q * 4 + r;
      float msk = (roff[row + 1] > roff[row]) ? 0.5f : 0.0f;
#pragma unroll
      for (int jt = 0; jt < 4; ++jt) {
        float val = acc[jt][r] + bv2[jt];
        float res = fmaf(msk, val, 0.5f * x0[(size_t)row * 64 + jt * 16 + m16]);
        myl[(q * 4 + r) * 68 + jt * 16 + m16] = res;
      }
    }
    h8 t0, t1;
#pragma unroll
    for (int j = 0; j < 8; ++j) t0[j] = (_Float16)myl[m16 * 68 + q * 8 + j];
#pragma unroll
    for (int j = 0; j < 8; ++j) t1[j] = (_Float16)myl[m16 * 68 + 32 + q * 8 + j];
#pragma unroll
    for (int jt = 0; jt < 4; ++jt) {
      acc[jt] = zero4();
      acc[jt] = MFMA(t0, w3[jt * 2 + 0], acc[jt]);
      acc[jt] = MFMA(t1, w3[jt * 2 + 1], acc[jt]);
    }
#pragma unroll
    for (int jt = 0; jt < 4; ++jt)
#pragma unroll
      for (int r = 0; r < 4; ++r)
        x[(size_t)(rbase + q * 4 + r) * 64 + jt * 16 + m16] = fmaxf(acc[jt][r] + bv3[jt], 0.0f);
  }
}

// ---- classifier (unchanged) ----
__global__ void __launch_bounds__(256) classifier_mfma(const float* __restrict__ x,
    const _Float16* __restrict__ wbuf, const float* __restrict__ bc1,
    const float* __restrict__ bc2, float* __restrict__ out, int ntiles) {
  __shared__ float lds[4][16 * 68];
  int l = threadIdx.x & 63, q = l >> 4, m16 = l & 15, wv = threadIdx.x >> 6;
  int wid = (blockIdx.x * blockDim.x + threadIdx.x) >> 6;
  int nw = (gridDim.x * blockDim.x) >> 6;
  const h8* w1p = (const h8*)(wbuf + OFF_C1);
  const h8* w2p = (const h8*)(wbuf + OFF_C2);
  h8 w1[8], w2[4];
#pragma unroll
  for (int f = 0; f < 8; ++f) w1[f] = w1p[f * 64 + l];
#pragma unroll
  for (int f = 0; f < 4; ++f) w2[f] = w2p[f * 64 + l];
  float bv1[4], bv2[2];
#pragma unroll
  for (int jt = 0; jt < 4; ++jt) bv1[jt] = bc1[jt * 16 + m16];
#pragma unroll
  for (int jt = 0; jt < 2; ++jt) bv2[jt] = bc2[jt * 16 + m16];
  float* myl = lds[wv];
  for (int t = wid; t < ntiles; t += nw) {
    int rbase = t * 16;
    const float* rp = x + (size_t)(rbase + m16) * 64 + q * 8;
    h8 a0 = ld_a32(rp), a1 = ld_a32(rp + 32);
    f4 acc[4];
#pragma unroll
    for (int jt = 0; jt < 4; ++jt) {
      acc[jt] = zero4();
      acc[jt] = MFMA(a0, w1[jt * 2 + 0], acc[jt]);
      acc[jt] = MFMA(a1, w1[jt * 2 + 1], acc[jt]);
    }
#pragma unroll
    for (int jt = 0; jt < 4; ++jt)
#pragma unroll
      for (int r = 0; r < 4; ++r)
        myl[(q * 4 + r) * 68 + jt * 16 + m16] = fmaxf(acc[jt][r] + bv1[jt], 0.0f);
    h8 t0, t1;
#pragma unroll
    for (int j = 0; j < 8; ++j) t0[j] = (_Float16)myl[m16 * 68 + q * 8 + j];
#pragma unroll
    for (int j = 0; j < 8; ++j) t1[j] = (_Float16)myl[m16 * 68 + 32 + q * 8 + j];
    f4 o[2];
#pragma unroll
    for (int jt = 0; jt < 2; ++jt) {
      o[jt] = zero4();
      o[jt] = MFMA(t0, w2[jt * 2 + 0], o[jt]);
      o[jt] = MFMA(t1, w2[jt * 2 + 1], o[jt]);
    }
#pragma unroll
    for (int jt = 0; jt < 2; ++jt)
#pragma unroll
      for (int r = 0; r < 4; ++r)
        out[(size_t)(rbase + q * 4 + r) * 32 + jt * 16 + m16] = o[jt][r] + bv2[jt];
  }
}

// ---- per-graph mean readout (unchanged) ----
__global__ void __launch_bounds__(256) readout_k(const float* __restrict__ xc,
    const int* __restrict__ batch, int n, float* __restrict__ out) {
  __shared__ float part[8][32];
  int g = blockIdx.x;
  int lo = lbound(batch, n, g);
  int hi = lbound(batch, n, g + 1);
  int j = threadIdx.x & 31, r = threadIdx.x >> 5;
  float acc = 0.0f;
  for (int i = lo + r; i < hi; i += 8) acc += xc[(size_t)i * 32 + j];
  part[r][j] = acc;
  __syncthreads();
  if (threadIdx.x < 32) {
    float s = 0.0f;
#pragma unroll
    for (int rr = 0; rr < 8; ++rr) s += part[rr][j];
    out[g * 32 + j] = (hi > lo) ? s / (float)(hi - lo) : 0.0f;
  }
}

extern "C" void kernel_launch(void* const* d_in, const int* in_sizes, int n_in,
                              void* d_out, int out_size, void* d_ws, size_t ws_size,
                              hipStream_t stream) {
  const float* X    = (const float*)d_in[0];
  const int*   src  = (const int*)d_in[1];
  const int*   dst  = (const int*)d_in[2];
  const int*   batch= (const int*)d_in[3];
  const float* W_in = (const float*)d_in[4];
  const float* b_in = (const float*)d_in[5];
  const float* W1a  = (const float*)d_in[6];
  const float* b1a  = (const float*)d_in[7];
  const float* W1b  = (const float*)d_in[8];
  const float* b1b  = (const float*)d_in[9];
  const float* W2   = (const float*)d_in[10];
  const float* b2   = (const float*)d_in[11];
  const float* W3   = (const float*)d_in[12];
  const float* b3   = (const float*)d_in[13];
  const float* Wc1  = (const float*)d_in[14];
  const float* bc1  = (const float*)d_in[15];
  const float* Wc2  = (const float*)d_in[16];
  const float* bc2  = (const float*)d_in[17];
  float* out = (float*)d_out;

  // workspace layout (~83 MB)
  float* p  = (float*)d_ws;
  float* x  = p; p += (size_t)NN * 64;            // 25.6 MB
  float* x0 = p; p += (size_t)NN * 64;            // 25.6 MB (aliased as classifier out later)
  __half* hz = (__half*)p; p += (size_t)NN * 32;  // 12.8 MB: h then z
  __half* Xe = (__half*)p; p += (size_t)NE * 32;  // 6.4 MB
  float* invE = p; p += NE;
  _Float16* wbuf = (_Float16*)p; p += WBUF_HALVES / 2 + 16;
  int* q     = (int*)p;
  int* cnt   = q; q += NE;
  int* off   = q; q += NE;
  int* cc    = q; q += 256;       // coarse cursors
  int* roff  = q; q += NN + 1;
  int* csr   = q; q += NZ;        // 5.12 MB
  unsigned int* words = (unsigned int*)q; q += NZ;  // 5.12 MB
  int* bsum  = q; q += 256;
  __half* h = hz;
  __half* z = hz;           // alias: h fully consumed by ve_pull before zgather writes z
  float* outc = x0;         // alias: x0 dead after last catmm_w3

  // CSR-by-dst build (binned) + row offsets + weight prep
  hipMemsetAsync(cnt, 0, (size_t)NE * sizeof(int), stream);
  count_k<<<(NZ + 255) / 256, 256, 0, stream>>>(dst, cnt, NZ);
  bsum_k<<<NB, 256, 0, stream>>>(cnt, bsum, NE);
  bscan_k<<<1, 256, 0, stream>>>(bsum, NB);
  csroff_k<<<NB, 256, 0, stream>>>(cnt, bsum, off, invE, NE);
  initcc_k<<<1, 256, 0, stream>>>(off, cc);
  binA_k<<<NBLK_A, 256, 0, stream>>>(src, dst, cc, words);
  binB_k<<<CB, 256, 0, stream>>>(words, off, csr, NE, NZ);
  rowoff_diff_k<<<(NZ + 255) / 256, 256, 0, stream>>>(src, roff, NN, NZ);
  prep_w_k<<<68, 64, 0, stream>>>(W_in, W1a, W1b, W2, W3, Wc1, Wc2, wbuf);

  mm_in_mfma<<<1563, 256, 0, stream>>>(X, wbuf, b_in, x, x0, NTILE);

  for (int l = 0; l < 2; ++l) {
    mm_dual_mfma<<<1563, 256, 0, stream>>>(x, wbuf, b1a, b1b, h, NTILE);
    ve_pull_k<<<(NE + 3) / 4, 256, 0, stream>>>(h, csr, off, cnt, invE, Xe, NE);
    zgather_k<<<(NN + 3) / 4, 256, 0, stream>>>(Xe, dst, roff, z, NN);
    catmm_w3_mfma<<<1563, 256, 0, stream>>>(x, z, x0, roff, wbuf, b2, b3, NTILE);
  }

  classifier_mfma<<<1563, 256, 0, stream>>>(x, wbuf, bc1, bc2, outc, NTILE);
  readout_k<<<NG, 256, 0, stream>>>(outc, batch, NN, out);
}

// Round 9
// 424.189 us; speedup vs baseline: 2.0663x; 1.1378x over previous
//
#include <hip/hip_runtime.h>
#include <hip/hip_fp16.h>

// EquivSetGNN forward, MI355X.
// R9: counting pass eliminated. count_k (57us, 40MB WRITE from cross-XCD atomic
// line-bouncing) + bsum/bscan/csroff/initcc removed. binA bins into fixed-capacity
// bucket regions (8192 >= 6530+20sigma); binB derives per-edge histogram, LDS
// 256-scan, off[] and invE[] from its LDS-resident bucket, then exact-scatters.
// ve_pull uses off[w]/off[w+1] (off has NE+1 entries). Rest unchanged from R8.

constexpr int NN = 100000;   // nodes
constexpr int NE = 50000;    // hyperedges
constexpr int NZ = 1280000;  // incidences
constexpr int NG = 256;      // graphs
constexpr int NTILE = NN / 16;  // 6250 row-tiles of 16
constexpr int CB = 196;         // coarse buckets = ceil(NE/256)
constexpr int CAP = 8192;       // bucket region capacity (words)
constexpr int CHUNK = 4000;
constexpr int NBLK_A = NZ / CHUNK;  // 320

typedef _Float16 h8 __attribute__((ext_vector_type(8)));
typedef float f4 __attribute__((ext_vector_type(4)));

constexpr int OFF_IN  = 0;
constexpr int OFF_1A  = 8192;
constexpr int OFF_1B  = 12288;
constexpr int OFF_W2  = 16384;
constexpr int OFF_W3  = 24576;
constexpr int OFF_C1  = 28672;
constexpr int OFF_C2  = 32768;
constexpr int WBUF_HALVES = 34816;

__device__ __forceinline__ int lbound(const int* a, int n, int v) {
  int lo = 0, hi = n;
  while (lo < hi) { int m = (lo + hi) >> 1; if (a[m] < v) lo = m + 1; else hi = m; }
  return lo;
}

__device__ __forceinline__ f4 zero4() { f4 z; z[0]=0.f; z[1]=0.f; z[2]=0.f; z[3]=0.f; return z; }

__device__ __forceinline__ h8 ld_a32(const float* p) {
  const f4* v = (const f4*)p;
  f4 lo = v[0], hi = v[1];
  h8 r;
  r[0]=(_Float16)lo[0]; r[1]=(_Float16)lo[1]; r[2]=(_Float16)lo[2]; r[3]=(_Float16)lo[3];
  r[4]=(_Float16)hi[0]; r[5]=(_Float16)hi[1]; r[6]=(_Float16)hi[2]; r[7]=(_Float16)hi[3];
  return r;
}

#define MFMA(a, b, c) __builtin_amdgcn_mfma_f32_16x16x32_f16((a), (b), (c), 0, 0, 0)

// ---- Pass A: coarse bin into fixed-capacity regions, packed ((dst&255)<<24 | src) ----
__global__ void __launch_bounds__(256) binA_k(const int* __restrict__ src,
    const int* __restrict__ dst, int* __restrict__ bcnt, unsigned int* __restrict__ words) {
  __shared__ int cnt[CB];
  __shared__ int base[CB];
  int t = threadIdx.x;
  int start = blockIdx.x * CHUNK;
  for (int i = t; i < CB; i += 256) cnt[i] = 0;
  __syncthreads();
  for (int i = start + t; i < start + CHUNK; i += 256)
    atomicAdd(&cnt[dst[i] >> 8], 1);
  __syncthreads();
  for (int i = t; i < CB; i += 256) base[i] = atomicAdd(&bcnt[i], cnt[i]);
  __syncthreads();
  for (int i = t; i < CB; i += 256) cnt[i] = 0;  // reuse as cursor
  __syncthreads();
  for (int i = start + t; i < start + CHUNK; i += 256) {
    int d = dst[i];
    int b = d >> 8;
    int p = base[b] + atomicAdd(&cnt[b], 1);
    words[(size_t)b * CAP + p] = (unsigned)src[i] | ((unsigned)(d & 255) << 24);
  }
}

// ---- exclusive scan of bcnt[CB] -> bbase[CB]; one block ----
__global__ void bscan196_k(const int* __restrict__ bcnt, int* __restrict__ bbase) {
  __shared__ int sh[256];
  int t = threadIdx.x;
  int my = (t < CB) ? bcnt[t] : 0;
  sh[t] = my;
  __syncthreads();
  for (int ofs = 1; ofs < 256; ofs <<= 1) {
    int v = (t >= ofs) ? sh[t - ofs] : 0;
    __syncthreads();
    sh[t] += v;
    __syncthreads();
  }
  if (t < CB) bbase[t] = sh[t] - my;
}

// ---- Pass B: per bucket — histogram, 256-scan, off/invE, exact scatter, copy-out ----
__global__ void __launch_bounds__(256) binB_k(const unsigned int* __restrict__ words,
    const int* __restrict__ bcnt, const int* __restrict__ bbase,
    int* __restrict__ off, float* __restrict__ invE, int* __restrict__ csr,
    int ne, int nnz) {
  __shared__ int buf[CAP];
  __shared__ int hist[256];
  __shared__ int sh[256];
  __shared__ int cur[256];
  int b = blockIdx.x, t = threadIdx.x;
  int e0 = b << 8;
  int ecnt = min(256, ne - e0);
  int cntb = bcnt[b];
  int gbase = bbase[b];
  const unsigned int* wp = words + (size_t)b * CAP;
  hist[t] = 0;
  __syncthreads();
  for (int i = t; i < cntb; i += 256) atomicAdd(&hist[wp[i] >> 24], 1);
  __syncthreads();
  int c = hist[t];
  sh[t] = c;
  __syncthreads();
  for (int ofs = 1; ofs < 256; ofs <<= 1) {
    int v = (t >= ofs) ? sh[t - ofs] : 0;
    __syncthreads();
    sh[t] += v;
    __syncthreads();
  }
  int excl = sh[t] - c;
  if (t < ecnt) {
    off[e0 + t] = gbase + excl;
    invE[e0 + t] = 1.0f / (float)max(c, 1);
  }
  if (b == CB - 1 && t == 0) off[ne] = nnz;
  cur[t] = excl;
  __syncthreads();
  for (int i = t; i < cntb; i += 256) {
    unsigned w = wp[i];
    int s = (int)(w & 0xFFFFFFu);
    int p = atomicAdd(&cur[w >> 24], 1);
    if (p < CAP) buf[p] = s;
    else csr[gbase + p] = s;  // statistically never
  }
  __syncthreads();
  int lim = min(cntb, CAP);
  for (int i = t; i < lim; i += 256) csr[gbase + i] = buf[i];
}

__global__ void rowoff_diff_k(const int* __restrict__ src, int* __restrict__ roff,
                              int n, int nnz) {
  int i = blockIdx.x * blockDim.x + threadIdx.x;
  if (i >= nnz) return;
  int s = src[i];
  int prev = (i == 0) ? -1 : src[i - 1];
  for (int v = prev + 1; v <= s; ++v) roff[v] = i;
  if (i == nnz - 1) {
    for (int v = s + 1; v <= n; ++v) roff[v] = nnz;
  }
}

// ---- weight prep (unchanged) ----
__global__ void prep_w_k(const float* __restrict__ W_in, const float* __restrict__ W1a,
                         const float* __restrict__ W1b, const float* __restrict__ W2,
                         const float* __restrict__ W3,  const float* __restrict__ Wc1,
                         const float* __restrict__ Wc2, _Float16* __restrict__ wbuf) {
  int b = blockIdx.x, l = threadIdx.x;
  const float* src; int K, J; _Float16* dst; int tile;
  if      (b < 16) { src = W_in; K = 128; J = 64; dst = wbuf + OFF_IN; tile = b; }
  else if (b < 24) { src = W1a;  K = 64;  J = 64; dst = wbuf + OFF_1A; tile = b - 16; }
  else if (b < 32) { src = W1b;  K = 64;  J = 64; dst = wbuf + OFF_1B; tile = b - 24; }
  else if (b < 48) { src = W2;   K = 128; J = 64; dst = wbuf + OFF_W2; tile = b - 32; }
  else if (b < 56) { src = W3;   K = 64;  J = 64; dst = wbuf + OFF_W3; tile = b - 48; }
  else if (b < 64) { src = Wc1;  K = 64;  J = 64; dst = wbuf + OFF_C1; tile = b - 56; }
  else             { src = Wc2;  K = 64;  J = 32; dst = wbuf + OFF_C2; tile = b - 64; }
  int KS = K / 32;
  int jt = tile / KS, ks = tile % KS;
  int q = l >> 4, m = l & 15;
#pragma unroll
  for (int j = 0; j < 8; ++j)
    dst[((size_t)tile * 64 + l) * 8 + j] =
        (_Float16)src[(size_t)(ks * 32 + q * 8 + j) * J + jt * 16 + m];
}

// ---- x = relu(X @ W_in + b); x0 = x. (unchanged) ----
__global__ void __launch_bounds__(256) mm_in_mfma(const float* __restrict__ A,
    const _Float16* __restrict__ wbuf, const float* __restrict__ b,
    float* __restrict__ C, float* __restrict__ C2, int ntiles) {
  int l = threadIdx.x & 63, q = l >> 4, m16 = l & 15;
  int wid = (blockIdx.x * blockDim.x + threadIdx.x) >> 6;
  int nw = (gridDim.x * blockDim.x) >> 6;
  const h8* wf = (const h8*)(wbuf + OFF_IN);
  h8 w[16];
#pragma unroll
  for (int f = 0; f < 16; ++f) w[f] = wf[f * 64 + l];
  float bv[4];
#pragma unroll
  for (int jt = 0; jt < 4; ++jt) bv[jt] = b[jt * 16 + m16];
  for (int t = wid; t < ntiles; t += nw) {
    int rbase = t * 16;
    const float* rp = A + (size_t)(rbase + m16) * 128 + q * 8;
    h8 a0 = ld_a32(rp), a1 = ld_a32(rp + 32), a2 = ld_a32(rp + 64), a3 = ld_a32(rp + 96);
    f4 acc[4];
#pragma unroll
    for (int jt = 0; jt < 4; ++jt) {
      acc[jt] = zero4();
      acc[jt] = MFMA(a0, w[jt * 4 + 0], acc[jt]);
      acc[jt] = MFMA(a1, w[jt * 4 + 1], acc[jt]);
      acc[jt] = MFMA(a2, w[jt * 4 + 2], acc[jt]);
      acc[jt] = MFMA(a3, w[jt * 4 + 3], acc[jt]);
    }
#pragma unroll
    for (int jt = 0; jt < 4; ++jt)
#pragma unroll
      for (int r = 0; r < 4; ++r) {
        float v = fmaxf(acc[jt][r] + bv[jt], 0.0f);
        size_t idx = (size_t)(rbase + q * 4 + r) * 64 + jt * 16 + m16;
        C[idx] = v; C2[idx] = v;
      }
  }
}

// ---- h = relu(x@W1a+b1a)@W1b + b1b (unchanged) ----
__global__ void __launch_bounds__(256) mm_dual_mfma(const float* __restrict__ x,
    const _Float16* __restrict__ wbuf, const float* __restrict__ b1a,
    const float* __restrict__ b1b, __half* __restrict__ h, int ntiles) {
  __shared__ float lds[4][16 * 68];
  int l = threadIdx.x & 63, q = l >> 4, m16 = l & 15, wv = threadIdx.x >> 6;
  int wid = (blockIdx.x * blockDim.x + threadIdx.x) >> 6;
  int nw = (gridDim.x * blockDim.x) >> 6;
  const h8* wap = (const h8*)(wbuf + OFF_1A);
  const h8* wbp = (const h8*)(wbuf + OFF_1B);
  h8 wa[8], wb[8];
#pragma unroll
  for (int f = 0; f < 8; ++f) { wa[f] = wap[f * 64 + l]; wb[f] = wbp[f * 64 + l]; }
  float bav[4], bbv[4];
#pragma unroll
  for (int jt = 0; jt < 4; ++jt) { bav[jt] = b1a[jt * 16 + m16]; bbv[jt] = b1b[jt * 16 + m16]; }
  float* myl = lds[wv];
  for (int t = wid; t < ntiles; t += nw) {
    int rbase = t * 16;
    const float* rp = x + (size_t)(rbase + m16) * 64 + q * 8;
    h8 a0 = ld_a32(rp), a1 = ld_a32(rp + 32);
    f4 acc[4];
#pragma unroll
    for (int jt = 0; jt < 4; ++jt) {
      acc[jt] = zero4();
      acc[jt] = MFMA(a0, wa[jt * 2 + 0], acc[jt]);
      acc[jt] = MFMA(a1, wa[jt * 2 + 1], acc[jt]);
    }
#pragma unroll
    for (int jt = 0; jt < 4; ++jt)
#pragma unroll
      for (int r = 0; r < 4; ++r)
        myl[(q * 4 + r) * 68 + jt * 16 + m16] = fmaxf(acc[jt][r] + bav[jt], 0.0f);
    h8 t0, t1;
#pragma unroll
    for (int j = 0; j < 8; ++j) t0[j] = (_Float16)myl[m16 * 68 + q * 8 + j];
#pragma unroll
    for (int j = 0; j < 8; ++j) t1[j] = (_Float16)myl[m16 * 68 + 32 + q * 8 + j];
#pragma unroll
    for (int jt = 0; jt < 4; ++jt) {
      acc[jt] = zero4();
      acc[jt] = MFMA(t0, wb[jt * 2 + 0], acc[jt]);
      acc[jt] = MFMA(t1, wb[jt * 2 + 1], acc[jt]);
    }
#pragma unroll
    for (int jt = 0; jt < 4; ++jt)
#pragma unroll
      for (int r = 0; r < 4; ++r)
        h[(size_t)(rbase + q * 4 + r) * 64 + jt * 16 + m16] = __float2half(acc[jt][r] + bbv[jt]);
  }
}

// ---- V->E pull: off[w]/off[w+1] (cnt array dropped) ----
__global__ void __launch_bounds__(256) ve_pull_k(const __half* __restrict__ h,
    const int* __restrict__ csr, const int* __restrict__ off,
    const float* __restrict__ invE, __half* __restrict__ Xe, int e) {
  int lane = threadIdx.x & 63;
  int w = (blockIdx.x * blockDim.x + threadIdx.x) >> 6;
  if (w >= e) return;
  int lo = off[w], end = off[w + 1];
  int g = lane >> 3, c = lane & 7;
  float acc[8];
#pragma unroll
  for (int j = 0; j < 8; ++j) acc[j] = 0.0f;
  for (int i = lo + g; i < end; i += 8) {
    int r = csr[i];
    h8 v = *(const h8*)(h + (size_t)r * 64 + c * 8);
#pragma unroll
    for (int j = 0; j < 8; ++j) acc[j] += (float)v[j];
  }
#pragma unroll
  for (int j = 0; j < 8; ++j) {
    acc[j] += __shfl_xor(acc[j], 8);
    acc[j] += __shfl_xor(acc[j], 16);
    acc[j] += __shfl_xor(acc[j], 32);
  }
  if (g == 0) {
    float s = invE[w];
    h8 o;
#pragma unroll
    for (int j = 0; j < 8; ++j) o[j] = (_Float16)(acc[j] * s);
    *(h8*)(Xe + (size_t)w * 64 + c * 8) = o;
  }
}

// ---- E->V pull (unchanged) ----
__global__ void __launch_bounds__(256) zgather_k(const __half* __restrict__ Xe,
    const int* __restrict__ dstArr, const int* __restrict__ roff,
    __half* __restrict__ z, int n) {
  int lane = threadIdx.x & 63;
  int w = (blockIdx.x * blockDim.x + threadIdx.x) >> 6;
  if (w >= n) return;
  int lo = roff[w], hi = roff[w + 1];
  int g = lane >> 3, c = lane & 7;
  float acc[8];
#pragma unroll
  for (int j = 0; j < 8; ++j) acc[j] = 0.0f;
  for (int i = lo + g; i < hi; i += 8) {
    int r = dstArr[i];
    h8 v = *(const h8*)(Xe + (size_t)r * 64 + c * 8);
#pragma unroll
    for (int j = 0; j < 8; ++j) acc[j] += (float)v[j];
  }
#pragma unroll
  for (int j = 0; j < 8; ++j) {
    acc[j] += __shfl_xor(acc[j], 8);
    acc[j] += __shfl_xor(acc[j], 16);
    acc[j] += __shfl_xor(acc[j], 32);
  }
  if (g == 0) {
    float s = (hi > lo) ? 1.0f / (float)(hi - lo) : 0.0f;
    h8 o;
#pragma unroll
    for (int j = 0; j < 8; ++j) o[j] = (_Float16)(acc[j] * s);
    *(h8*)(z + (size_t)w * 64 + c * 8) = o;
  }
}

// ---- catmm + W3 (unchanged) ----
__global__ void __launch_bounds__(256) catmm_w3_mfma(float* __restrict__ x,
    const __half* __restrict__ z, const float* __restrict__ x0,
    const int* __restrict__ roff, const _Float16* __restrict__ wbuf,
    const float* __restrict__ b2, const float* __restrict__ b3, int ntiles) {
  __shared__ float lds[4][16 * 68];
  int l = threadIdx.x & 63, q = l >> 4, m16 = l & 15, wv = threadIdx.x >> 6;
  int wid = (blockIdx.x * blockDim.x + threadIdx.x) >> 6;
  int nw = (gridDim.x * blockDim.x) >> 6;
  const h8* w2p = (const h8*)(wbuf + OFF_W2);
  const h8* w3p = (const h8*)(wbuf + OFF_W3);
  h8 w2[16], w3[8];
#pragma unroll
  for (int f = 0; f < 16; ++f) w2[f] = w2p[f * 64 + l];
#pragma unroll
  for (int f = 0; f < 8; ++f) w3[f] = w3p[f * 64 + l];
  float bv2[4], bv3[4];
#pragma unroll
  for (int jt = 0; jt < 4; ++jt) { bv2[jt] = b2[jt * 16 + m16]; bv3[jt] = b3[jt * 16 + m16]; }
  float* myl = lds[wv];
  for (int t = wid; t < ntiles; t += nw) {
    int rbase = t * 16;
    const float* rp = x + (size_t)(rbase + m16) * 64 + q * 8;
    h8 a0 = ld_a32(rp), a1 = ld_a32(rp + 32);
    const h8* zp = (const h8*)(z + (size_t)(rbase + m16) * 64 + q * 8);
    h8 az0 = zp[0], az1 = zp[2];
    f4 acc[4];
#pragma unroll
    for (int jt = 0; jt < 4; ++jt) {
      acc[jt] = zero4();
      acc[jt] = MFMA(a0,  w2[jt * 4 + 0], acc[jt]);
      acc[jt] = MFMA(a1,  w2[jt * 4 + 1], acc[jt]);
      acc[jt] = MFMA(az0, w2[jt * 4 + 2], acc[jt]);
      acc[jt] = MFMA(az1, w2[jt * 4 + 3], acc[jt]);
    }
#pragma unroll
    for (int r = 0; r < 4; ++r) {
      int row = rbase + q * 4 + r;
      float msk = (roff[row + 1] > roff[row]) ? 0.5f : 0.0f;
#pragma unroll
      for (int jt = 0; jt < 4; ++jt) {
        float val = acc[jt][r] + bv2[jt];
        float res = fmaf(msk, val, 0.5f * x0[(size_t)row * 64 + jt * 16 + m16]);
        myl[(q * 4 + r) * 68 + jt * 16 + m16] = res;
      }
    }
    h8 t0, t1;
#pragma unroll
    for (int j = 0; j < 8; ++j) t0[j] = (_Float16)myl[m16 * 68 + q * 8 + j];
#pragma unroll
    for (int j = 0; j < 8; ++j) t1[j] = (_Float16)myl[m16 * 68 + 32 + q * 8 + j];
#pragma unroll
    for (int jt = 0; jt < 4; ++jt) {
      acc[jt] = zero4();
      acc[jt] = MFMA(t0, w3[jt * 2 + 0], acc[jt]);
      acc[jt] = MFMA(t1, w3[jt * 2 + 1], acc[jt]);
    }
#pragma unroll
    for (int jt = 0; jt < 4; ++jt)
#pragma unroll
      for (int r = 0; r < 4; ++r)
        x[(size_t)(rbase + q * 4 + r) * 64 + jt * 16 + m16] = fmaxf(acc[jt][r] + bv3[jt], 0.0f);
  }
}

// ---- classifier (unchanged) ----
__global__ void __launch_bounds__(256) classifier_mfma(const float* __restrict__ x,
    const _Float16* __restrict__ wbuf, const float* __restrict__ bc1,
    const float* __restrict__ bc2, float* __restrict__ out, int ntiles) {
  __shared__ float lds[4][16 * 68];
  int l = threadIdx.x & 63, q = l >> 4, m16 = l & 15, wv = threadIdx.x >> 6;
  int wid = (blockIdx.x * blockDim.x + threadIdx.x) >> 6;
  int nw = (gridDim.x * blockDim.x) >> 6;
  const h8* w1p = (const h8*)(wbuf + OFF_C1);
  const h8* w2p = (const h8*)(wbuf + OFF_C2);
  h8 w1[8], w2[4];
#pragma unroll
  for (int f = 0; f < 8; ++f) w1[f] = w1p[f * 64 + l];
#pragma unroll
  for (int f = 0; f < 4; ++f) w2[f] = w2p[f * 64 + l];
  float bv1[4], bv2[2];
#pragma unroll
  for (int jt = 0; jt < 4; ++jt) bv1[jt] = bc1[jt * 16 + m16];
#pragma unroll
  for (int jt = 0; jt < 2; ++jt) bv2[jt] = bc2[jt * 16 + m16];
  float* myl = lds[wv];
  for (int t = wid; t < ntiles; t += nw) {
    int rbase = t * 16;
    const float* rp = x + (size_t)(rbase + m16) * 64 + q * 8;
    h8 a0 = ld_a32(rp), a1 = ld_a32(rp + 32);
    f4 acc[4];
#pragma unroll
    for (int jt = 0; jt < 4; ++jt) {
      acc[jt] = zero4();
      acc[jt] = MFMA(a0, w1[jt * 2 + 0], acc[jt]);
      acc[jt] = MFMA(a1, w1[jt * 2 + 1], acc[jt]);
    }
#pragma unroll
    for (int jt = 0; jt < 4; ++jt)
#pragma unroll
      for (int r = 0; r < 4; ++r)
        myl[(q * 4 + r) * 68 + jt * 16 + m16] = fmaxf(acc[jt][r] + bv1[jt], 0.0f);
    h8 t0, t1;
#pragma unroll
    for (int j = 0; j < 8; ++j) t0[j] = (_Float16)myl[m16 * 68 + q * 8 + j];
#pragma unroll
    for (int j = 0; j < 8; ++j) t1[j] = (_Float16)myl[m16 * 68 + 32 + q * 8 + j];
    f4 o[2];
#pragma unroll
    for (int jt = 0; jt < 2; ++jt) {
      o[jt] = zero4();
      o[jt] = MFMA(t0, w2[jt * 2 + 0], o[jt]);
      o[jt] = MFMA(t1, w2[jt * 2 + 1], o[jt]);
    }
#pragma unroll
    for (int jt = 0; jt < 2; ++jt)
#pragma unroll
      for (int r = 0; r < 4; ++r)
        out[(size_t)(rbase + q * 4 + r) * 32 + jt * 16 + m16] = o[jt][r] + bv2[jt];
  }
}

// ---- per-graph mean readout (unchanged) ----
__global__ void __launch_bounds__(256) readout_k(const float* __restrict__ xc,
    const int* __restrict__ batch, int n, float* __restrict__ out) {
  __shared__ float part[8][32];
  int g = blockIdx.x;
  int lo = lbound(batch, n, g);
  int hi = lbound(batch, n, g + 1);
  int j = threadIdx.x & 31, r = threadIdx.x >> 5;
  float acc = 0.0f;
  for (int i = lo + r; i < hi; i += 8) acc += xc[(size_t)i * 32 + j];
  part[r][j] = acc;
  __syncthreads();
  if (threadIdx.x < 32) {
    float s = 0.0f;
#pragma unroll
    for (int rr = 0; rr < 8; ++rr) s += part[rr][j];
    out[g * 32 + j] = (hi > lo) ? s / (float)(hi - lo) : 0.0f;
  }
}

extern "C" void kernel_launch(void* const* d_in, const int* in_sizes, int n_in,
                              void* d_out, int out_size, void* d_ws, size_t ws_size,
                              hipStream_t stream) {
  const float* X    = (const float*)d_in[0];
  const int*   src  = (const int*)d_in[1];
  const int*   dst  = (const int*)d_in[2];
  const int*   batch= (const int*)d_in[3];
  const float* W_in = (const float*)d_in[4];
  const float* b_in = (const float*)d_in[5];
  const float* W1a  = (const float*)d_in[6];
  const float* b1a  = (const float*)d_in[7];
  const float* W1b  = (const float*)d_in[8];
  const float* b1b  = (const float*)d_in[9];
  const float* W2   = (const float*)d_in[10];
  const float* b2   = (const float*)d_in[11];
  const float* W3   = (const float*)d_in[12];
  const float* b3   = (const float*)d_in[13];
  const float* Wc1  = (const float*)d_in[14];
  const float* bc1  = (const float*)d_in[15];
  const float* Wc2  = (const float*)d_in[16];
  const float* bc2  = (const float*)d_in[17];
  float* out = (float*)d_out;

  // workspace layout (~84 MB)
  float* p  = (float*)d_ws;
  float* x  = p; p += (size_t)NN * 64;            // 25.6 MB
  float* x0 = p; p += (size_t)NN * 64;            // 25.6 MB (aliased as classifier out later)
  __half* hz = (__half*)p; p += (size_t)NN * 32;  // 12.8 MB: h then z
  __half* Xe = (__half*)p; p += (size_t)NE * 32;  // 6.4 MB
  float* invE = p; p += NE;
  _Float16* wbuf = (_Float16*)p; p += WBUF_HALVES / 2 + 16;
  int* q     = (int*)p;
  int* off   = q; q += NE + 1;
  int* bcnt  = q; q += 256;
  int* bbase = q; q += 256;
  int* roff  = q; q += NN + 1;
  int* csr   = q; q += NZ;        // 5.12 MB
  unsigned int* words = (unsigned int*)q; q += CB * CAP;  // 6.4 MB
  __half* h = hz;
  __half* z = hz;           // alias: h fully consumed by ve_pull before zgather writes z
  float* outc = x0;         // alias: x0 dead after last catmm_w3

  // CSR-by-dst build (two-pass binned, no counting pre-pass)
  hipMemsetAsync(bcnt, 0, 256 * sizeof(int), stream);
  binA_k<<<NBLK_A, 256, 0, stream>>>(src, dst, bcnt, words);
  bscan196_k<<<1, 256, 0, stream>>>(bcnt, bbase);
  binB_k<<<CB, 256, 0, stream>>>(words, bcnt, bbase, off, invE, csr, NE, NZ);
  rowoff_diff_k<<<(NZ + 255) / 256, 256, 0, stream>>>(src, roff, NN, NZ);
  prep_w_k<<<68, 64, 0, stream>>>(W_in, W1a, W1b, W2, W3, Wc1, Wc2, wbuf);

  mm_in_mfma<<<1563, 256, 0, stream>>>(X, wbuf, b_in, x, x0, NTILE);

  for (int l = 0; l < 2; ++l) {
    mm_dual_mfma<<<1563, 256, 0, stream>>>(x, wbuf, b1a, b1b, h, NTILE);
    ve_pull_k<<<(NE + 3) / 4, 256, 0, stream>>>(h, csr, off, invE, Xe, NE);
    zgather_k<<<(NN + 3) / 4, 256, 0, stream>>>(Xe, dst, roff, z, NN);
    catmm_w3_mfma<<<1563, 256, 0, stream>>>(x, z, x0, roff, wbuf, b2, b3, NTILE);
  }

  classifier_mfma<<<1563, 256, 0, stream>>>(x, wbuf, bc1, bc2, outc, NTILE);
  readout_k<<<NG, 256, 0, stream>>>(outc, batch, NN, out);
}

// Round 10
// 393.401 us; speedup vs baseline: 2.2281x; 1.0783x over previous
//
#include <hip/hip_runtime.h>
#include <hip/hip_fp16.h>

// EquivSetGNN forward, MI355X.
// R10: (1) x/x0/classifier-out stored fp16 — every consumer converts to fp16 for
// MFMA anyway, so this halves streaming traffic in 6 kernels at ~zero extra error.
// (2) bucket-base scan folded into binB (LDS 196-scan per block); bcnt zeroing
// folded into rowoff_diff block 0. 15 -> 13 dispatches. (3) az1 z-fragment offset
// fixed to explicit +32 halves. Gathers + binned CSR build otherwise unchanged.

constexpr int NN = 100000;   // nodes
constexpr int NE = 50000;    // hyperedges
constexpr int NZ = 1280000;  // incidences
constexpr int NG = 256;      // graphs
constexpr int NTILE = NN / 16;  // 6250 row-tiles of 16
constexpr int CB = 196;         // coarse buckets = ceil(NE/256)
constexpr int CAP = 8192;       // bucket region capacity (words)
constexpr int CHUNK = 4000;
constexpr int NBLK_A = NZ / CHUNK;  // 320

typedef _Float16 h8 __attribute__((ext_vector_type(8)));
typedef float f4 __attribute__((ext_vector_type(4)));

constexpr int OFF_IN  = 0;
constexpr int OFF_1A  = 8192;
constexpr int OFF_1B  = 12288;
constexpr int OFF_W2  = 16384;
constexpr int OFF_W3  = 24576;
constexpr int OFF_C1  = 28672;
constexpr int OFF_C2  = 32768;
constexpr int WBUF_HALVES = 34816;

__device__ __forceinline__ int lbound(const int* a, int n, int v) {
  int lo = 0, hi = n;
  while (lo < hi) { int m = (lo + hi) >> 1; if (a[m] < v) lo = m + 1; else hi = m; }
  return lo;
}

__device__ __forceinline__ f4 zero4() { f4 z; z[0]=0.f; z[1]=0.f; z[2]=0.f; z[3]=0.f; return z; }

__device__ __forceinline__ h8 ld_a32(const float* p) {
  const f4* v = (const f4*)p;
  f4 lo = v[0], hi = v[1];
  h8 r;
  r[0]=(_Float16)lo[0]; r[1]=(_Float16)lo[1]; r[2]=(_Float16)lo[2]; r[3]=(_Float16)lo[3];
  r[4]=(_Float16)hi[0]; r[5]=(_Float16)hi[1]; r[6]=(_Float16)hi[2]; r[7]=(_Float16)hi[3];
  return r;
}

#define MFMA(a, b, c) __builtin_amdgcn_mfma_f32_16x16x32_f16((a), (b), (c), 0, 0, 0)

// ---- Pass A: coarse bin into fixed-capacity regions, packed ((dst&255)<<24 | src) ----
__global__ void __launch_bounds__(256) binA_k(const int* __restrict__ src,
    const int* __restrict__ dst, int* __restrict__ bcnt, unsigned int* __restrict__ words) {
  __shared__ int cnt[CB];
  __shared__ int base[CB];
  int t = threadIdx.x;
  int start = blockIdx.x * CHUNK;
  for (int i = t; i < CB; i += 256) cnt[i] = 0;
  __syncthreads();
  for (int i = start + t; i < start + CHUNK; i += 256)
    atomicAdd(&cnt[dst[i] >> 8], 1);
  __syncthreads();
  for (int i = t; i < CB; i += 256) base[i] = atomicAdd(&bcnt[i], cnt[i]);
  __syncthreads();
  for (int i = t; i < CB; i += 256) cnt[i] = 0;  // reuse as cursor
  __syncthreads();
  for (int i = start + t; i < start + CHUNK; i += 256) {
    int d = dst[i];
    int b = d >> 8;
    int p = base[b] + atomicAdd(&cnt[b], 1);
    words[(size_t)b * CAP + p] = (unsigned)src[i] | ((unsigned)(d & 255) << 24);
  }
}

// ---- Pass B: per bucket — bucket-base scan, per-edge histogram, 256-scan,
//      off/invE, exact scatter via LDS, coalesced copy-out ----
__global__ void __launch_bounds__(256) binB_k(const unsigned int* __restrict__ words,
    const int* __restrict__ bcnt,
    int* __restrict__ off, float* __restrict__ invE, int* __restrict__ csr,
    int ne, int nnz) {
  __shared__ int buf[CAP];
  __shared__ int hist[256];
  __shared__ int sh[256];
  __shared__ int cur[256];
  __shared__ int shb[256];
  int b = blockIdx.x, t = threadIdx.x;
  int e0 = b << 8;
  int ecnt = min(256, ne - e0);
  int cntb = bcnt[b];
  // bucket base = exclusive prefix sum of bcnt[0..b)
  shb[t] = (t < CB) ? bcnt[t] : 0;
  __syncthreads();
  for (int ofs = 1; ofs < 256; ofs <<= 1) {
    int v = (t >= ofs) ? shb[t - ofs] : 0;
    __syncthreads();
    shb[t] += v;
    __syncthreads();
  }
  int gbase = shb[b] - cntb;
  const unsigned int* wp = words + (size_t)b * CAP;
  hist[t] = 0;
  __syncthreads();
  for (int i = t; i < cntb; i += 256) atomicAdd(&hist[wp[i] >> 24], 1);
  __syncthreads();
  int c = hist[t];
  sh[t] = c;
  __syncthreads();
  for (int ofs = 1; ofs < 256; ofs <<= 1) {
    int v = (t >= ofs) ? sh[t - ofs] : 0;
    __syncthreads();
    sh[t] += v;
    __syncthreads();
  }
  int excl = sh[t] - c;
  if (t < ecnt) {
    off[e0 + t] = gbase + excl;
    invE[e0 + t] = 1.0f / (float)max(c, 1);
  }
  if (b == CB - 1 && t == 0) off[ne] = nnz;
  cur[t] = excl;
  __syncthreads();
  for (int i = t; i < cntb; i += 256) {
    unsigned w = wp[i];
    int s = (int)(w & 0xFFFFFFu);
    int p = atomicAdd(&cur[w >> 24], 1);
    if (p < CAP) buf[p] = s;
    else csr[gbase + p] = s;  // statistically never
  }
  __syncthreads();
  int lim = min(cntb, CAP);
  for (int i = t; i < lim; i += 256) csr[gbase + i] = buf[i];
}

// roff from sorted src; block 0 also zeroes bcnt (runs before binA in stream order)
__global__ void rowoff_diff_k(const int* __restrict__ src, int* __restrict__ roff,
                              int* __restrict__ bcnt, int n, int nnz) {
  if (blockIdx.x == 0 && threadIdx.x < 256) bcnt[threadIdx.x] = 0;
  int i = blockIdx.x * blockDim.x + threadIdx.x;
  if (i >= nnz) return;
  int s = src[i];
  int prev = (i == 0) ? -1 : src[i - 1];
  for (int v = prev + 1; v <= s; ++v) roff[v] = i;
  if (i == nnz - 1) {
    for (int v = s + 1; v <= n; ++v) roff[v] = nnz;
  }
}

// ---- weight prep (unchanged) ----
__global__ void prep_w_k(const float* __restrict__ W_in, const float* __restrict__ W1a,
                         const float* __restrict__ W1b, const float* __restrict__ W2,
                         const float* __restrict__ W3,  const float* __restrict__ Wc1,
                         const float* __restrict__ Wc2, _Float16* __restrict__ wbuf) {
  int b = blockIdx.x, l = threadIdx.x;
  const float* src; int K, J; _Float16* dst; int tile;
  if      (b < 16) { src = W_in; K = 128; J = 64; dst = wbuf + OFF_IN; tile = b; }
  else if (b < 24) { src = W1a;  K = 64;  J = 64; dst = wbuf + OFF_1A; tile = b - 16; }
  else if (b < 32) { src = W1b;  K = 64;  J = 64; dst = wbuf + OFF_1B; tile = b - 24; }
  else if (b < 48) { src = W2;   K = 128; J = 64; dst = wbuf + OFF_W2; tile = b - 32; }
  else if (b < 56) { src = W3;   K = 64;  J = 64; dst = wbuf + OFF_W3; tile = b - 48; }
  else if (b < 64) { src = Wc1;  K = 64;  J = 64; dst = wbuf + OFF_C1; tile = b - 56; }
  else             { src = Wc2;  K = 64;  J = 32; dst = wbuf + OFF_C2; tile = b - 64; }
  int KS = K / 32;
  int jt = tile / KS, ks = tile % KS;
  int q = l >> 4, m = l & 15;
#pragma unroll
  for (int j = 0; j < 8; ++j)
    dst[((size_t)tile * 64 + l) * 8 + j] =
        (_Float16)src[(size_t)(ks * 32 + q * 8 + j) * J + jt * 16 + m];
}

// ---- x = relu(X @ W_in + b); x0 = x. fp16 outputs ----
__global__ void __launch_bounds__(256) mm_in_mfma(const float* __restrict__ A,
    const _Float16* __restrict__ wbuf, const float* __restrict__ b,
    __half* __restrict__ C, __half* __restrict__ C2, int ntiles) {
  int l = threadIdx.x & 63, q = l >> 4, m16 = l & 15;
  int wid = (blockIdx.x * blockDim.x + threadIdx.x) >> 6;
  int nw = (gridDim.x * blockDim.x) >> 6;
  const h8* wf = (const h8*)(wbuf + OFF_IN);
  h8 w[16];
#pragma unroll
  for (int f = 0; f < 16; ++f) w[f] = wf[f * 64 + l];
  float bv[4];
#pragma unroll
  for (int jt = 0; jt < 4; ++jt) bv[jt] = b[jt * 16 + m16];
  for (int t = wid; t < ntiles; t += nw) {
    int rbase = t * 16;
    const float* rp = A + (size_t)(rbase + m16) * 128 + q * 8;
    h8 a0 = ld_a32(rp), a1 = ld_a32(rp + 32), a2 = ld_a32(rp + 64), a3 = ld_a32(rp + 96);
    f4 acc[4];
#pragma unroll
    for (int jt = 0; jt < 4; ++jt) {
      acc[jt] = zero4();
      acc[jt] = MFMA(a0, w[jt * 4 + 0], acc[jt]);
      acc[jt] = MFMA(a1, w[jt * 4 + 1], acc[jt]);
      acc[jt] = MFMA(a2, w[jt * 4 + 2], acc[jt]);
      acc[jt] = MFMA(a3, w[jt * 4 + 3], acc[jt]);
    }
#pragma unroll
    for (int jt = 0; jt < 4; ++jt)
#pragma unroll
      for (int r = 0; r < 4; ++r) {
        __half v = __float2half(fmaxf(acc[jt][r] + bv[jt], 0.0f));
        size_t idx = (size_t)(rbase + q * 4 + r) * 64 + jt * 16 + m16;
        C[idx] = v; C2[idx] = v;
      }
  }
}

// ---- h = relu(x@W1a+b1a)@W1b + b1b; fp16 in/out ----
__global__ void __launch_bounds__(256) mm_dual_mfma(const __half* __restrict__ x,
    const _Float16* __restrict__ wbuf, const float* __restrict__ b1a,
    const float* __restrict__ b1b, __half* __restrict__ h, int ntiles) {
  __shared__ float lds[4][16 * 68];
  int l = threadIdx.x & 63, q = l >> 4, m16 = l & 15, wv = threadIdx.x >> 6;
  int wid = (blockIdx.x * blockDim.x + threadIdx.x) >> 6;
  int nw = (gridDim.x * blockDim.x) >> 6;
  const h8* wap = (const h8*)(wbuf + OFF_1A);
  const h8* wbp = (const h8*)(wbuf + OFF_1B);
  h8 wa[8], wb[8];
#pragma unroll
  for (int f = 0; f < 8; ++f) { wa[f] = wap[f * 64 + l]; wb[f] = wbp[f * 64 + l]; }
  float bav[4], bbv[4];
#pragma unroll
  for (int jt = 0; jt < 4; ++jt) { bav[jt] = b1a[jt * 16 + m16]; bbv[jt] = b1b[jt * 16 + m16]; }
  float* myl = lds[wv];
  for (int t = wid; t < ntiles; t += nw) {
    int rbase = t * 16;
    const __half* rp = x + (size_t)(rbase + m16) * 64 + q * 8;
    h8 a0 = *(const h8*)rp, a1 = *(const h8*)(rp + 32);
    f4 acc[4];
#pragma unroll
    for (int jt = 0; jt < 4; ++jt) {
      acc[jt] = zero4();
      acc[jt] = MFMA(a0, wa[jt * 2 + 0], acc[jt]);
      acc[jt] = MFMA(a1, wa[jt * 2 + 1], acc[jt]);
    }
#pragma unroll
    for (int jt = 0; jt < 4; ++jt)
#pragma unroll
      for (int r = 0; r < 4; ++r)
        myl[(q * 4 + r) * 68 + jt * 16 + m16] = fmaxf(acc[jt][r] + bav[jt], 0.0f);
    h8 t0, t1;
#pragma unroll
    for (int j = 0; j < 8; ++j) t0[j] = (_Float16)myl[m16 * 68 + q * 8 + j];
#pragma unroll
    for (int j = 0; j < 8; ++j) t1[j] = (_Float16)myl[m16 * 68 + 32 + q * 8 + j];
#pragma unroll
    for (int jt = 0; jt < 4; ++jt) {
      acc[jt] = zero4();
      acc[jt] = MFMA(t0, wb[jt * 2 + 0], acc[jt]);
      acc[jt] = MFMA(t1, wb[jt * 2 + 1], acc[jt]);
    }
#pragma unroll
    for (int jt = 0; jt < 4; ++jt)
#pragma unroll
      for (int r = 0; r < 4; ++r)
        h[(size_t)(rbase + q * 4 + r) * 64 + jt * 16 + m16] = __float2half(acc[jt][r] + bbv[jt]);
  }
}

// ---- V->E pull (unchanged) ----
__global__ void __launch_bounds__(256) ve_pull_k(const __half* __restrict__ h,
    const int* __restrict__ csr, const int* __restrict__ off,
    const float* __restrict__ invE, __half* __restrict__ Xe, int e) {
  int lane = threadIdx.x & 63;
  int w = (blockIdx.x * blockDim.x + threadIdx.x) >> 6;
  if (w >= e) return;
  int lo = off[w], end = off[w + 1];
  int g = lane >> 3, c = lane & 7;
  float acc[8];
#pragma unroll
  for (int j = 0; j < 8; ++j) acc[j] = 0.0f;
  for (int i = lo + g; i < end; i += 8) {
    int r = csr[i];
    h8 v = *(const h8*)(h + (size_t)r * 64 + c * 8);
#pragma unroll
    for (int j = 0; j < 8; ++j) acc[j] += (float)v[j];
  }
#pragma unroll
  for (int j = 0; j < 8; ++j) {
    acc[j] += __shfl_xor(acc[j], 8);
    acc[j] += __shfl_xor(acc[j], 16);
    acc[j] += __shfl_xor(acc[j], 32);
  }
  if (g == 0) {
    float s = invE[w];
    h8 o;
#pragma unroll
    for (int j = 0; j < 8; ++j) o[j] = (_Float16)(acc[j] * s);
    *(h8*)(Xe + (size_t)w * 64 + c * 8) = o;
  }
}

// ---- E->V pull (unchanged) ----
__global__ void __launch_bounds__(256) zgather_k(const __half* __restrict__ Xe,
    const int* __restrict__ dstArr, const int* __restrict__ roff,
    __half* __restrict__ z, int n) {
  int lane = threadIdx.x & 63;
  int w = (blockIdx.x * blockDim.x + threadIdx.x) >> 6;
  if (w >= n) return;
  int lo = roff[w], hi = roff[w + 1];
  int g = lane >> 3, c = lane & 7;
  float acc[8];
#pragma unroll
  for (int j = 0; j < 8; ++j) acc[j] = 0.0f;
  for (int i = lo + g; i < hi; i += 8) {
    int r = dstArr[i];
    h8 v = *(const h8*)(Xe + (size_t)r * 64 + c * 8);
#pragma unroll
    for (int j = 0; j < 8; ++j) acc[j] += (float)v[j];
  }
#pragma unroll
  for (int j = 0; j < 8; ++j) {
    acc[j] += __shfl_xor(acc[j], 8);
    acc[j] += __shfl_xor(acc[j], 16);
    acc[j] += __shfl_xor(acc[j], 32);
  }
  if (g == 0) {
    float s = (hi > lo) ? 1.0f / (float)(hi - lo) : 0.0f;
    h8 o;
#pragma unroll
    for (int j = 0; j < 8; ++j) o[j] = (_Float16)(acc[j] * s);
    *(h8*)(z + (size_t)w * 64 + c * 8) = o;
  }
}

// ---- fused: res = 0.5*x0 + mask*0.5*(cat(x,z)@W2+b2); x = relu(res@W3+b3). fp16 x/x0 ----
__global__ void __launch_bounds__(256) catmm_w3_mfma(__half* __restrict__ x,
    const __half* __restrict__ z, const __half* __restrict__ x0,
    const int* __restrict__ roff, const _Float16* __restrict__ wbuf,
    const float* __restrict__ b2, const float* __restrict__ b3, int ntiles) {
  __shared__ float lds[4][16 * 68];
  int l = threadIdx.x & 63, q = l >> 4, m16 = l & 15, wv = threadIdx.x >> 6;
  int wid = (blockIdx.x * blockDim.x + threadIdx.x) >> 6;
  int nw = (gridDim.x * blockDim.x) >> 6;
  const h8* w2p = (const h8*)(wbuf + OFF_W2);
  const h8* w3p = (const h8*)(wbuf + OFF_W3);
  h8 w2[16], w3[8];
#pragma unroll
  for (int f = 0; f < 16; ++f) w2[f] = w2p[f * 64 + l];
#pragma unroll
  for (int f = 0; f < 8; ++f) w3[f] = w3p[f * 64 + l];
  float bv2[4], bv3[4];
#pragma unroll
  for (int jt = 0; jt < 4; ++jt) { bv2[jt] = b2[jt * 16 + m16]; bv3[jt] = b3[jt * 16 + m16]; }
  float* myl = lds[wv];
  for (int t = wid; t < ntiles; t += nw) {
    int rbase = t * 16;
    const __half* rp = x + (size_t)(rbase + m16) * 64 + q * 8;
    h8 a0 = *(const h8*)rp, a1 = *(const h8*)(rp + 32);
    const __half* zr = z + (size_t)(rbase + m16) * 64;
    h8 az0 = *(const h8*)(zr + q * 8), az1 = *(const h8*)(zr + 32 + q * 8);
    f4 acc[4];
#pragma unroll
    for (int jt = 0; jt < 4; ++jt) {
      acc[jt] = zero4();
      acc[jt] = MFMA(a0,  w2[jt * 4 + 0], acc[jt]);
      acc[jt] = MFMA(a1,  w2[jt * 4 + 1], acc[jt]);
      acc[jt] = MFMA(az0, w2[jt * 4 + 2], acc[jt]);
      acc[jt] = MFMA(az1, w2[jt * 4 + 3], acc[jt]);
    }
#pragma unroll
    for (int r = 0; r < 4; ++r) {
      int row = rbase + q * 4 + r;
      float msk = (roff[row + 1] > roff[row]) ? 0.5f : 0.0f;
#pragma unroll
      for (int jt = 0; jt < 4; ++jt) {
        float val = acc[jt][r] + bv2[jt];
        float x0v = __half2float(x0[(size_t)row * 64 + jt * 16 + m16]);
        myl[(q * 4 + r) * 68 + jt * 16 + m16] = fmaf(msk, val, 0.5f * x0v);
      }
    }
    h8 t0, t1;
#pragma unroll
    for (int j = 0; j < 8; ++j) t0[j] = (_Float16)myl[m16 * 68 + q * 8 + j];
#pragma unroll
    for (int j = 0; j < 8; ++j) t1[j] = (_Float16)myl[m16 * 68 + 32 + q * 8 + j];
#pragma unroll
    for (int jt = 0; jt < 4; ++jt) {
      acc[jt] = zero4();
      acc[jt] = MFMA(t0, w3[jt * 2 + 0], acc[jt]);
      acc[jt] = MFMA(t1, w3[jt * 2 + 1], acc[jt]);
    }
#pragma unroll
    for (int jt = 0; jt < 4; ++jt)
#pragma unroll
      for (int r = 0; r < 4; ++r)
        x[(size_t)(rbase + q * 4 + r) * 64 + jt * 16 + m16] =
            __float2half(fmaxf(acc[jt][r] + bv3[jt], 0.0f));
  }
}

// ---- classifier: fp16 in/out ----
__global__ void __launch_bounds__(256) classifier_mfma(const __half* __restrict__ x,
    const _Float16* __restrict__ wbuf, const float* __restrict__ bc1,
    const float* __restrict__ bc2, __half* __restrict__ out, int ntiles) {
  __shared__ float lds[4][16 * 68];
  int l = threadIdx.x & 63, q = l >> 4, m16 = l & 15, wv = threadIdx.x >> 6;
  int wid = (blockIdx.x * blockDim.x + threadIdx.x) >> 6;
  int nw = (gridDim.x * blockDim.x) >> 6;
  const h8* w1p = (const h8*)(wbuf + OFF_C1);
  const h8* w2p = (const h8*)(wbuf + OFF_C2);
  h8 w1[8], w2[4];
#pragma unroll
  for (int f = 0; f < 8; ++f) w1[f] = w1p[f * 64 + l];
#pragma unroll
  for (int f = 0; f < 4; ++f) w2[f] = w2p[f * 64 + l];
  float bv1[4], bv2[2];
#pragma unroll
  for (int jt = 0; jt < 4; ++jt) bv1[jt] = bc1[jt * 16 + m16];
#pragma unroll
  for (int jt = 0; jt < 2; ++jt) bv2[jt] = bc2[jt * 16 + m16];
  float* myl = lds[wv];
  for (int t = wid; t < ntiles; t += nw) {
    int rbase = t * 16;
    const __half* rp = x + (size_t)(rbase + m16) * 64 + q * 8;
    h8 a0 = *(const h8*)rp, a1 = *(const h8*)(rp + 32);
    f4 acc[4];
#pragma unroll
    for (int jt = 0; jt < 4; ++jt) {
      acc[jt] = zero4();
      acc[jt] = MFMA(a0, w1[jt * 2 + 0], acc[jt]);
      acc[jt] = MFMA(a1, w1[jt * 2 + 1], acc[jt]);
    }
#pragma unroll
    for (int jt = 0; jt < 4; ++jt)
#pragma unroll
      for (int r = 0; r < 4; ++r)
        myl[(q * 4 + r) * 68 + jt * 16 + m16] = fmaxf(acc[jt][r] + bv1[jt], 0.0f);
    h8 t0, t1;
#pragma unroll
    for (int j = 0; j < 8; ++j) t0[j] = (_Float16)myl[m16 * 68 + q * 8 + j];
#pragma unroll
    for (int j = 0; j < 8; ++j) t1[j] = (_Float16)myl[m16 * 68 + 32 + q * 8 + j];
    f4 o[2];
#pragma unroll
    for (int jt = 0; jt < 2; ++jt) {
      o[jt] = zero4();
      o[jt] = MFMA(t0, w2[jt * 2 + 0], o[jt]);
      o[jt] = MFMA(t1, w2[jt * 2 + 1], o[jt]);
    }
#pragma unroll
    for (int jt = 0; jt < 2; ++jt)
#pragma unroll
      for (int r = 0; r < 4; ++r)
        out[(size_t)(rbase + q * 4 + r) * 32 + jt * 16 + m16] =
            __float2half(o[jt][r] + bv2[jt]);
  }
}

// ---- per-graph mean readout; fp16 input ----
__global__ void __launch_bounds__(256) readout_k(const __half* __restrict__ xc,
    const int* __restrict__ batch, int n, float* __restrict__ out) {
  __shared__ float part[8][32];
  int g = blockIdx.x;
  int lo = lbound(batch, n, g);
  int hi = lbound(batch, n, g + 1);
  int j = threadIdx.x & 31, r = threadIdx.x >> 5;
  float acc = 0.0f;
  for (int i = lo + r; i < hi; i += 8) acc += __half2float(xc[(size_t)i * 32 + j]);
  part[r][j] = acc;
  __syncthreads();
  if (threadIdx.x < 32) {
    float s = 0.0f;
#pragma unroll
    for (int rr = 0; rr < 8; ++rr) s += part[rr][j];
    out[g * 32 + j] = (hi > lo) ? s / (float)(hi - lo) : 0.0f;
  }
}

extern "C" void kernel_launch(void* const* d_in, const int* in_sizes, int n_in,
                              void* d_out, int out_size, void* d_ws, size_t ws_size,
                              hipStream_t stream) {
  const float* X    = (const float*)d_in[0];
  const int*   src  = (const int*)d_in[1];
  const int*   dst  = (const int*)d_in[2];
  const int*   batch= (const int*)d_in[3];
  const float* W_in = (const float*)d_in[4];
  const float* b_in = (const float*)d_in[5];
  const float* W1a  = (const float*)d_in[6];
  const float* b1a  = (const float*)d_in[7];
  const float* W1b  = (const float*)d_in[8];
  const float* b1b  = (const float*)d_in[9];
  const float* W2   = (const float*)d_in[10];
  const float* b2   = (const float*)d_in[11];
  const float* W3   = (const float*)d_in[12];
  const float* b3   = (const float*)d_in[13];
  const float* Wc1  = (const float*)d_in[14];
  const float* bc1  = (const float*)d_in[15];
  const float* Wc2  = (const float*)d_in[16];
  const float* bc2  = (const float*)d_in[17];
  float* out = (float*)d_out;

  // workspace layout (~57 MB)
  float* p  = (float*)d_ws;
  __half* x  = (__half*)p; p += (size_t)NN * 32;  // 12.8 MB fp16
  __half* x0 = (__half*)p; p += (size_t)NN * 32;  // 12.8 MB fp16 (aliased as outc later)
  __half* hz = (__half*)p; p += (size_t)NN * 32;  // 12.8 MB: h then z
  __half* Xe = (__half*)p; p += (size_t)NE * 32;  // 6.4 MB
  float* invE = p; p += NE;
  _Float16* wbuf = (_Float16*)p; p += WBUF_HALVES / 2 + 16;
  int* q     = (int*)p;
  int* off   = q; q += NE + 1;
  int* bcnt  = q; q += 256;
  int* roff  = q; q += NN + 1;
  int* csr   = q; q += NZ;        // 5.12 MB
  unsigned int* words = (unsigned int*)q; q += CB * CAP;  // 6.4 MB
  __half* h = hz;
  __half* z = hz;           // alias: h fully consumed by ve_pull before zgather writes z
  __half* outc = x0;        // alias: x0 dead after last catmm_w3

  // CSR-by-dst build (binned, no counting pre-pass) + row offsets + weight prep
  rowoff_diff_k<<<(NZ + 255) / 256, 256, 0, stream>>>(src, roff, bcnt, NN, NZ);
  binA_k<<<NBLK_A, 256, 0, stream>>>(src, dst, bcnt, words);
  binB_k<<<CB, 256, 0, stream>>>(words, bcnt, off, invE, csr, NE, NZ);
  prep_w_k<<<68, 64, 0, stream>>>(W_in, W1a, W1b, W2, W3, Wc1, Wc2, wbuf);

  mm_in_mfma<<<1563, 256, 0, stream>>>(X, wbuf, b_in, x, x0, NTILE);

  for (int l = 0; l < 2; ++l) {
    mm_dual_mfma<<<1563, 256, 0, stream>>>(x, wbuf, b1a, b1b, h, NTILE);
    ve_pull_k<<<(NE + 3) / 4, 256, 0, stream>>>(h, csr, off, invE, Xe, NE);
    zgather_k<<<(NN + 3) / 4, 256, 0, stream>>>(Xe, dst, roff, z, NN);
    catmm_w3_mfma<<<1563, 256, 0, stream>>>(x, z, x0, roff, wbuf, b2, b3, NTILE);
  }

  classifier_mfma<<<1563, 256, 0, stream>>>(x, wbuf, bc1, bc2, outc, NTILE);
  readout_k<<<NG, 256, 0, stream>>>(outc, batch, NN, out);
}